// Round 7
// baseline (428.005 us; speedup 1.0000x reference)
//
#include <hip/hip_runtime.h>
#include <cstdint>
#include <cstddef>

// ---------- types ----------
typedef unsigned short u16;
typedef float  floatx4 __attribute__((ext_vector_type(4)));
typedef short  short8  __attribute__((ext_vector_type(8)));
typedef u16    usx4    __attribute__((ext_vector_type(4)));
typedef u16    usx8    __attribute__((ext_vector_type(8)));
typedef unsigned uintx2 __attribute__((ext_vector_type(2)));

// fp32 -> bf16, round-to-nearest-even
__device__ __forceinline__ u16 f2b(float f) {
  unsigned u = __float_as_uint(f);
  unsigned r = u + 0x7fffu + ((u >> 16) & 1u);
  return (u16)(r >> 16);
}
__device__ __forceinline__ float b2f(u16 s) {
  return __uint_as_float(((unsigned)s) << 16);
}

// packed fp32x2 -> bf16x2 (hardware RNE); no builtin on gfx950 -> inline asm
__device__ __forceinline__ unsigned cvt_pk_bf16(float lo, float hi) {
  unsigned r;
  asm("v_cvt_pk_bf16_f32 %0, %1, %2" : "=v"(r) : "v"(lo), "v"(hi));
  return r;
}

// max across each 16-lane row via DPP (VALU-only)
__device__ __forceinline__ float rowmax16(float x) {
  int xi = __float_as_int(x), y;
  y = __builtin_amdgcn_update_dpp(xi, xi, 0xB1, 0xF, 0xF, false);  // quad_perm xor1
  x = fmaxf(x, __int_as_float(y)); xi = __float_as_int(x);
  y = __builtin_amdgcn_update_dpp(xi, xi, 0x4E, 0xF, 0xF, false);  // quad_perm xor2
  x = fmaxf(x, __int_as_float(y)); xi = __float_as_int(x);
  y = __builtin_amdgcn_update_dpp(xi, xi, 0x141, 0xF, 0xF, false); // row_half_mirror
  x = fmaxf(x, __int_as_float(y)); xi = __float_as_int(x);
  y = __builtin_amdgcn_update_dpp(xi, xi, 0x140, 0xF, 0xF, false); // row_mirror
  x = fmaxf(x, __int_as_float(y));
  return x;
}

// GPT-2 tanh-gelu, exact algebraic rewrite: 0.5x(1+tanh(u)) = x*sigmoid(2u)
__device__ __forceinline__ float gelu_f(float x) {
  const float k = 2.3022082f;  // 2*sqrt(2/pi)*log2(e)
  float u = x * (1.0f + 0.044715f * x * x);
  float t = __builtin_amdgcn_exp2f(-k * u);
  return x * __builtin_amdgcn_rcpf(1.0f + t);
}

// async global->LDS 16B: lds dst = wave-uniform base + lane*16 (HW rule)
__device__ __forceinline__ void gl2lds16(const u16* g, u16* l) {
  __builtin_amdgcn_global_load_lds(
      (const __attribute__((address_space(1))) unsigned int*)g,
      (__attribute__((address_space(3))) unsigned int*)l, 16, 0, 0);
}

// counted vmcnt wait + raw barrier (T4: younger loads stay in flight)
template<int N> __device__ __forceinline__ void wait_stage_barrier() {
  asm volatile("s_waitcnt vmcnt(%0)" :: "n"(N) : "memory");
  __builtin_amdgcn_s_barrier();
  __builtin_amdgcn_sched_barrier(0);
}
// raw barrier after compute, before re-staging the freed buffer
__device__ __forceinline__ void post_barrier() {
  __builtin_amdgcn_sched_barrier(0);
  __builtin_amdgcn_s_barrier();
  __builtin_amdgcn_sched_barrier(0);
}

#define C2SCALE 0.18033688011112042f  // (1/8) * log2(e)

// ---------- LayerNorm: one block per row of 1024, bf16 out ----------
__global__ __launch_bounds__(256) void ln_bf16_kernel(
    const float* __restrict__ in, const float* __restrict__ w,
    const float* __restrict__ b, u16* __restrict__ out)
{
  const int row = blockIdx.x;
  const int t = threadIdx.x;
  const float* p = in + (size_t)row * 1024 + t * 4;
  floatx4 v = *(const floatx4*)p;
  float s  = v.x + v.y + v.z + v.w;
  float ss = v.x*v.x + v.y*v.y + v.z*v.z + v.w*v.w;
  #pragma unroll
  for (int m = 1; m < 64; m <<= 1) {
    s  += __shfl_xor(s,  m);
    ss += __shfl_xor(ss, m);
  }
  __shared__ float red[8];
  if ((t & 63) == 0) { red[(t >> 6)*2] = s; red[(t >> 6)*2 + 1] = ss; }
  __syncthreads();
  s  = red[0] + red[2] + red[4] + red[6];
  ss = red[1] + red[3] + red[5] + red[7];
  const float mean = s * (1.0f / 1024.0f);
  const float var  = ss * (1.0f / 1024.0f) - mean * mean;
  const float rstd = rsqrtf(var + 1e-6f);
  floatx4 wv = *(const floatx4*)(w + t * 4);
  floatx4 bv = *(const floatx4*)(b + t * 4);
  usx4 o = { f2b(wv.x * ((v.x - mean) * rstd) + bv.x),
             f2b(wv.y * ((v.y - mean) * rstd) + bv.y),
             f2b(wv.z * ((v.z - mean) * rstd) + bv.z),
             f2b(wv.w * ((v.w - mean) * rstd) + bv.w) };
  *(usx4*)(out + (size_t)row * 1024 + t * 4) = o;
}

// ---------- fused K-split combine + LayerNorm (NP partials) ----------
template<int NP>
__global__ __launch_bounds__(256) void combine_ln_kernel(
    const u16* __restrict__ pp, size_t pstride,
    const float* __restrict__ res, const float* __restrict__ bias,
    const float* __restrict__ w, const float* __restrict__ b,
    float* __restrict__ hout, u16* __restrict__ yout)
{
  const int row = blockIdx.x;
  const int t = threadIdx.x;
  const size_t i0 = (size_t)row * 1024 + t * 4;
  floatx4 rv = *(const floatx4*)(res + i0);
  usx4 a[NP];
  #pragma unroll
  for (int z = 0; z < NP; ++z) a[z] = *(const usx4*)(pp + z * pstride + i0);
  floatx4 biasv = *(const floatx4*)(bias + t * 4);
  floatx4 v;
  #pragma unroll
  for (int i = 0; i < 4; ++i) {
    float acc = rv[i] + biasv[i];
    #pragma unroll
    for (int z = 0; z < NP; ++z) acc += b2f(a[z][i]);
    v[i] = acc;
  }
  *(floatx4*)(hout + i0) = v;

  float s  = v.x + v.y + v.z + v.w;
  float ss = v.x*v.x + v.y*v.y + v.z*v.z + v.w*v.w;
  #pragma unroll
  for (int m = 1; m < 64; m <<= 1) {
    s  += __shfl_xor(s,  m);
    ss += __shfl_xor(ss, m);
  }
  __shared__ float red[8];
  if ((t & 63) == 0) { red[(t >> 6)*2] = s; red[(t >> 6)*2 + 1] = ss; }
  __syncthreads();
  s  = red[0] + red[2] + red[4] + red[6];
  ss = red[1] + red[3] + red[5] + red[7];
  const float mean = s * (1.0f / 1024.0f);
  const float var  = ss * (1.0f / 1024.0f) - mean * mean;
  const float rstd = rsqrtf(var + 1e-6f);
  floatx4 wv = *(const floatx4*)(w + t * 4);
  floatx4 bv = *(const floatx4*)(b + t * 4);
  usx4 o = { f2b(wv.x * ((v.x - mean) * rstd) + bv.x),
             f2b(wv.y * ((v.y - mean) * rstd) + bv.y),
             f2b(wv.z * ((v.z - mean) * rstd) + bv.z),
             f2b(wv.w * ((v.w - mean) * rstd) + bv.w) };
  *(usx4*)(yout + i0) = o;
}

// ---------- weight transpose+convert: 4 weights in one launch ----------
__device__ __forceinline__ void wtrans_body(
    const float* __restrict__ in, u16* __restrict__ out, int K, int N,
    int bx, int by, int tx, int ty)
{
  __shared__ u16 tile[32][33];
  const int n0 = bx * 32, k0 = by * 32;
  #pragma unroll
  for (int i = 0; i < 4; ++i)
    tile[ty + i*8][tx] = f2b(in[(size_t)(k0 + ty + i*8) * N + n0 + tx]);
  __syncthreads();
  #pragma unroll
  for (int i = 0; i < 4; ++i)
    out[(size_t)(n0 + ty + i*8) * K + k0 + tx] = tile[tx][ty + i*8];
}

__global__ __launch_bounds__(256) void wtrans4_kernel(
    const float* __restrict__ w0, const float* __restrict__ w1,
    const float* __restrict__ w2, const float* __restrict__ w3,
    u16* __restrict__ o0, u16* __restrict__ o1,
    u16* __restrict__ o2, u16* __restrict__ o3)
{
  int blk = blockIdx.x;
  const int tx = threadIdx.x & 31, ty = threadIdx.x >> 5;
  if (blk < 3072) {
    wtrans_body(w0, o0, 1024, 3072, blk % 96, blk / 96, tx, ty);
  } else if (blk < 4096) {
    blk -= 3072; wtrans_body(w1, o1, 1024, 1024, blk % 32, blk / 32, tx, ty);
  } else if (blk < 8192) {
    blk -= 4096; wtrans_body(w2, o2, 1024, 4096, blk % 128, blk / 128, tx, ty);
  } else {
    blk -= 8192; wtrans_body(w3, o3, 4096, 1024, blk % 32, blk / 32, tx, ty);
  }
}

// ---------- 128x128 2-phase GEMM (round-3/5 verified) ----------
// FLAGS: 1 = gelu, 2 = +Res (fp32), 4 = bf16 out, 8 = scale cols<1024 by C2
template<int BM, int BN, int FLAGS, int MINW,
         int NX, int NY, int NZ, int RX, int RY, int RZ>
__global__ __launch_bounds__(256, MINW) void gemm_mfma_kernel(
    const u16* __restrict__ A, const u16* __restrict__ Bt,
    const float* __restrict__ bias, const float* __restrict__ Res,
    void* __restrict__ Cout, int M, int N, int K, int kLen, size_t zStride)
{
  constexpr int WM = BM / 2, WN = BN / 2;
  constexpr int MT = WM / 16, NT = WN / 16;
  constexpr int GX = NX / RX, GY = NY / RY, GZ = NZ / RZ;
  constexpr int ABUF = BM * 32, BBUF = BN * 32;
  constexpr int L = BM / 64 + BN / 64;
  __shared__ u16 As[2 * ABUF];
  __shared__ u16 Bs[2 * BBUF];

  const int lin = blockIdx.x + NX * (blockIdx.y + NY * blockIdx.z);
  const int xcd = lin & 7;
  const int idx = lin >> 3;
  const int rx = xcd % RX, ry = (xcd / RX) % RY, rz = xcd / (RX * RY);
  const int bx = rx * GX + idx % GX;
  const int by = ry * GY + (idx / GX) % GY;
  const int bz = rz * GZ + idx / (GX * GY);

  const int t = threadIdx.x;
  const int wave = t >> 6, lane = t & 63;
  const int quad = lane >> 4, l16 = lane & 15;
  const int wm = wave >> 1, wn = wave & 1;
  const int bm0 = by * BM, bn0 = bx * BN;
  const int kStart = bz * kLen;

  const int sRow = lane >> 2;
  const int sq   = (lane & 3) ^ ((lane >> 4) & 3);

  const u16* aG[BM / 64];
  u16* aL[BM / 64];
  #pragma unroll
  for (int j = 0; j < BM / 64; ++j) {
    const int band = j * 4 + wave;
    aG[j] = A + (size_t)(bm0 + band * 16 + sRow) * K + kStart + sq * 8;
    aL[j] = As + band * 512;
  }
  const u16* bG[BN / 64];
  u16* bL[BN / 64];
  #pragma unroll
  for (int j = 0; j < BN / 64; ++j) {
    const int band = j * 4 + wave;
    bG[j] = Bt + (size_t)(bn0 + band * 16 + sRow) * K + kStart + sq * 8;
    bL[j] = Bs + band * 512;
  }

  floatx4 acc[MT][NT] = {};
  const int rcol = (quad ^ (l16 >> 2)) << 3;

  auto stage = [&](int tile, int buf) {
    #pragma unroll
    for (int j = 0; j < BM / 64; ++j) gl2lds16(aG[j] + tile * 32, aL[j] + buf * ABUF);
    #pragma unroll
    for (int j = 0; j < BN / 64; ++j) gl2lds16(bG[j] + tile * 32, bL[j] + buf * BBUF);
  };
  auto compute = [&](int buf) {
    const u16* Asc = As + buf * ABUF;
    const u16* Bsc = Bs + buf * BBUF;
    short8 af[MT], bf[NT];
    #pragma unroll
    for (int mt = 0; mt < MT; ++mt)
      af[mt] = *(const short8*)&Asc[(wm*WM + mt*16 + l16) * 32 + rcol];
    #pragma unroll
    for (int nt = 0; nt < NT; ++nt)
      bf[nt] = *(const short8*)&Bsc[(wn*WN + nt*16 + l16) * 32 + rcol];
    __builtin_amdgcn_s_setprio(1);
    #pragma unroll
    for (int mt = 0; mt < MT; ++mt)
      #pragma unroll
      for (int nt = 0; nt < NT; ++nt)
        acc[mt][nt] = __builtin_amdgcn_mfma_f32_16x16x32_bf16(af[mt], bf[nt], acc[mt][nt], 0, 0, 0);
    __builtin_amdgcn_s_setprio(0);
  };

  const int nt = kLen >> 5;
  stage(0, 0);
  stage(1, 1);
  #pragma unroll 1
  for (int ti = 0; ti < nt - 2; ti += 2) {
    wait_stage_barrier<L>();
    compute(0);
    post_barrier();
    stage(ti + 2, 0);
    wait_stage_barrier<L>();
    compute(1);
    post_barrier();
    stage(ti + 3, 1);
  }
  wait_stage_barrier<L>();
  compute(0);
  wait_stage_barrier<0>();
  compute(1);

  const int orow0 = bm0 + wm * WM;
  const int ocol0 = bn0 + wn * WN;
  const size_t zoff = (size_t)bz * zStride;
  #pragma unroll
  for (int nt2 = 0; nt2 < NT; ++nt2) {
    const int col = ocol0 + nt2*16 + l16;
    const float bv = bias ? bias[col] : 0.0f;
    const float postscale = ((FLAGS & 8) && col < 1024) ? C2SCALE : 1.0f;
    #pragma unroll
    for (int mt = 0; mt < MT; ++mt) {
      #pragma unroll
      for (int r = 0; r < 4; ++r) {
        const int row = orow0 + mt*16 + quad*4 + r;
        float v = acc[mt][nt2][r] + bv;
        if (FLAGS & 1) v = gelu_f(v);
        if (FLAGS & 8) v *= postscale;
        if (FLAGS & 2) v += Res[(size_t)row * N + col];
        if (FLAGS & 4) ((u16*)Cout)[zoff + (size_t)row * N + col] = f2b(v);
        else           ((float*)Cout)[zoff + (size_t)row * N + col] = v;
      }
    }
  }
}

// ---------- 256x256 8-phase GEMM (round-6 verified schedule) ----------
// + stage-before-ds_read per phase (T3 recipe ordering; vmcnt counts identical)
// + LDS-staged coalesced C-store: wave-private 16x66 patch in the dead As[0]
//   region (last tile always reads buf 1 -> NT must be EVEN), usx8 row stores.
// FLAGS: 1 = gelu, 4 = bf16 out (required), 8 = scale cols<1024 by C2
template<int FLAGS, int NX, int NY, int NZ, int RX, int RY, int RZ>
__global__ __launch_bounds__(512, 2) void gemm256_kernel(
    const u16* __restrict__ A, const u16* __restrict__ Bt,
    const float* __restrict__ bias,
    void* __restrict__ Cout, int M, int N, int K, int kLen, size_t zStride)
{
  constexpr int SLOT = 256 * 32;            // u16 per K-half slot (16 KiB)
  constexpr int GX = NX / RX, GY = NY / RY, GZ = NZ / RZ;
  __shared__ u16 As[2][2][SLOT];
  __shared__ u16 Bs[2][2][SLOT];

  const int lin = blockIdx.x + NX * (blockIdx.y + NY * blockIdx.z);
  const int xcd = lin & 7;
  const int idx = lin >> 3;
  const int rx = xcd % RX, ry = (xcd / RX) % RY, rz = xcd / (RX * RY);
  const int bx = rx * GX + idx % GX;
  const int by = ry * GY + (idx / GX) % GY;
  const int bz = rz * GZ + idx / (GX * GY);

  const int t = threadIdx.x;                 // 0..511
  const int wave = t >> 6;                   // 0..7
  const int lane = t & 63;
  const int quad = lane >> 4, l16 = lane & 15;
  const int wm = wave >> 2;                  // 0..1
  const int wn = wave & 3;                   // 0..3
  const int bm0 = by * 256, bn0 = bx * 256;
  const int kStart = bz * kLen;

  const int sRow = lane >> 2;
  const int sq   = (lane & 3) ^ ((lane >> 3) & 3);

  const u16* aGb[2]; const u16* bGb[2];
  #pragma unroll
  for (int j = 0; j < 2; ++j) {
    const int band = wave * 2 + j;
    aGb[j] = A  + (size_t)(bm0 + band * 16 + sRow) * K + kStart + sq * 8;
    bGb[j] = Bt + (size_t)(bn0 + band * 16 + sRow) * K + kStart + sq * 8;
  }

  auto stageA = [&](int kt, int kk) {
    u16* dst = &As[kt & 1][kk][0];
    #pragma unroll
    for (int j = 0; j < 2; ++j)
      gl2lds16(aGb[j] + kt * 64 + kk * 32, dst + (wave * 2 + j) * 512);
  };
  auto stageB = [&](int kt, int kk) {
    u16* dst = &Bs[kt & 1][kk][0];
    #pragma unroll
    for (int j = 0; j < 2; ++j)
      gl2lds16(bGb[j] + kt * 64 + kk * 32, dst + (wave * 2 + j) * 512);
  };

  floatx4 acc[8][4] = {};
  const int rcol = (quad ^ ((l16 >> 1) & 3)) << 3;

  const int NT = kLen >> 6;                  // K-tiles of 64; EVEN at all call sites
  stageA(0, 0); stageB(0, 0); stageA(0, 1); stageB(0, 1);

  #pragma unroll 1
  for (int kt = 0; kt < NT; ++kt) {
    const int buf = kt & 1;
    const bool pf = (kt + 1 < NT);
    short8 af[4], bf[4];

    // W0: [kt,k0] ready ([kt,k1]'s 4 loads stay in flight)
    wait_stage_barrier<4>();
    // ---- P1: kk=0, mt 0-3 ----
    if (pf) stageA(kt + 1, 0);
    #pragma unroll
    for (int nt2 = 0; nt2 < 4; ++nt2)
      bf[nt2] = *(const short8*)&Bs[buf][0][(wn*64 + nt2*16 + l16) * 32 + rcol];
    #pragma unroll
    for (int mt = 0; mt < 4; ++mt)
      af[mt] = *(const short8*)&As[buf][0][(wm*128 + mt*16 + l16) * 32 + rcol];
    __builtin_amdgcn_s_barrier();
    asm volatile("s_waitcnt lgkmcnt(0)" ::: "memory");
    __builtin_amdgcn_sched_barrier(0);
    __builtin_amdgcn_s_setprio(1);
    #pragma unroll
    for (int mt = 0; mt < 4; ++mt)
      #pragma unroll
      for (int nt2 = 0; nt2 < 4; ++nt2)
        acc[mt][nt2] = __builtin_amdgcn_mfma_f32_16x16x32_bf16(af[mt], bf[nt2], acc[mt][nt2], 0, 0, 0);
    __builtin_amdgcn_s_setprio(0);
    __builtin_amdgcn_s_barrier();
    // ---- P2: kk=0, mt 4-7 (bf reused) ----
    if (pf) stageB(kt + 1, 0);
    #pragma unroll
    for (int mt = 0; mt < 4; ++mt)
      af[mt] = *(const short8*)&As[buf][0][(wm*128 + (mt+4)*16 + l16) * 32 + rcol];
    __builtin_amdgcn_s_barrier();
    asm volatile("s_waitcnt lgkmcnt(0)" ::: "memory");
    __builtin_amdgcn_sched_barrier(0);
    __builtin_amdgcn_s_setprio(1);
    #pragma unroll
    for (int mt = 0; mt < 4; ++mt)
      #pragma unroll
      for (int nt2 = 0; nt2 < 4; ++nt2)
        acc[mt+4][nt2] = __builtin_amdgcn_mfma_f32_16x16x32_bf16(af[mt], bf[nt2], acc[mt+4][nt2], 0, 0, 0);
    __builtin_amdgcn_s_setprio(0);
    // W1: [kt,k1] ready ([kt+1,k0] in flight; last tile: drain)
    if (pf) wait_stage_barrier<4>(); else wait_stage_barrier<0>();
    // ---- P3: kk=1, mt 0-3 ----
    if (pf) stageA(kt + 1, 1);
    #pragma unroll
    for (int nt2 = 0; nt2 < 4; ++nt2)
      bf[nt2] = *(const short8*)&Bs[buf][1][(wn*64 + nt2*16 + l16) * 32 + rcol];
    #pragma unroll
    for (int mt = 0; mt < 4; ++mt)
      af[mt] = *(const short8*)&As[buf][1][(wm*128 + mt*16 + l16) * 32 + rcol];
    __builtin_amdgcn_s_barrier();
    asm volatile("s_waitcnt lgkmcnt(0)" ::: "memory");
    __builtin_amdgcn_sched_barrier(0);
    __builtin_amdgcn_s_setprio(1);
    #pragma unroll
    for (int mt = 0; mt < 4; ++mt)
      #pragma unroll
      for (int nt2 = 0; nt2 < 4; ++nt2)
        acc[mt][nt2] = __builtin_amdgcn_mfma_f32_16x16x32_bf16(af[mt], bf[nt2], acc[mt][nt2], 0, 0, 0);
    __builtin_amdgcn_s_setprio(0);
    __builtin_amdgcn_s_barrier();
    // ---- P4: kk=1, mt 4-7 ----
    if (pf) stageB(kt + 1, 1);
    #pragma unroll
    for (int mt = 0; mt < 4; ++mt)
      af[mt] = *(const short8*)&As[buf][1][(wm*128 + (mt+4)*16 + l16) * 32 + rcol];
    __builtin_amdgcn_s_barrier();
    asm volatile("s_waitcnt lgkmcnt(0)" ::: "memory");
    __builtin_amdgcn_sched_barrier(0);
    __builtin_amdgcn_s_setprio(1);
    #pragma unroll
    for (int mt = 0; mt < 4; ++mt)
      #pragma unroll
      for (int nt2 = 0; nt2 < 4; ++nt2)
        acc[mt+4][nt2] = __builtin_amdgcn_mfma_f32_16x16x32_bf16(af[mt], bf[nt2], acc[mt+4][nt2], 0, 0, 0);
    __builtin_amdgcn_s_setprio(0);
  }

  // ---- coalesced epilogue ----
  // NT even -> last tile read As[1]/Bs[1]; As[0] area (32 KB) is dead.
  // Wave-private 16x66 u16 patch (66-stride spreads quad rows across banks).
  // No barriers needed: regions are disjoint per wave and vs As[1] readers.
  const int orow0 = bm0 + wm * 128;
  const int ocol0 = bn0 + wn * 64;
  const size_t zoff = (size_t)bz * zStride;
  u16* eb = &As[0][0][0] + wave * 1056;      // 16*66 u16 per wave

  float bvv[4]; float psv[4];
  #pragma unroll
  for (int nt2 = 0; nt2 < 4; ++nt2) {
    const int col = ocol0 + nt2*16 + l16;
    bvv[nt2] = bias ? bias[col] : 0.0f;
    psv[nt2] = ((FLAGS & 8) && col < 1024) ? C2SCALE : 1.0f;
  }
  #pragma unroll 1
  for (int mt = 0; mt < 8; ++mt) {
    #pragma unroll
    for (int nt2 = 0; nt2 < 4; ++nt2) {
      #pragma unroll
      for (int r = 0; r < 4; ++r) {
        float v = acc[mt][nt2][r] + bvv[nt2];
        if (FLAGS & 1) v = gelu_f(v);
        if (FLAGS & 8) v *= psv[nt2];
        eb[(quad*4 + r) * 66 + nt2*16 + l16] = f2b(v);
      }
    }
    #pragma unroll
    for (int half = 0; half < 2; ++half) {
      const int row = half*8 + (lane >> 3);
      const int co  = (lane & 7) * 8;
      usx8 val = *(const usx8*)&eb[row * 66 + co];
      *(usx8*)((u16*)Cout + zoff + (size_t)(orow0 + mt*16 + row) * N + ocol0 + co) = val;
    }
  }
}

// ---------- MFMA flash attention (causal), bf16, balanced + K-split ----------
// (round-3/5 verified version)
__global__ __launch_bounds__(256, 4) void attn_mfma_kernel(
    const u16* __restrict__ qkv, u16* __restrict__ opart, float* __restrict__ ml)
{
  __shared__ u16 Ks[64][72];
  __shared__ u16 Vt[64][72];
  __shared__ u16 Ps[64][72];

  const int t    = threadIdx.x;
  const int wave = t >> 6;
  const int lane = t & 63;
  const int quad = lane >> 4;
  const int l16  = lane & 15;
  const int pair = blockIdx.x >> 1;
  const int half = blockIdx.x & 1;
  const int h    = blockIdx.y;
  const int b    = blockIdx.z;

  const size_t base = (size_t)b * 2048 * 3072;
  const int qoff = h * 64;
  const int koff = 1024 + h * 64;
  const int voff = 2048 + h * 64;

  const int prow = t >> 2;
  const int scol = (t & 3) * 16;
  const int kmap = ((prow & 15) << 2) | (prow >> 4);
  const int kpair  = t & 31;
  const int vchunk = t >> 5;

  const size_t obase  = ((((size_t)half * 2 + b) * 16 + h) * 2048) * 64;
  const size_t mlbase = ((((size_t)half * 2 + b) * 16 + h) * 2048) * 2;

  short8 onesb;
  {
    const short v = (l16 == 0) ? (short)0x3F80 : (short)0;
    #pragma unroll
    for (int i = 0; i < 8; ++i) onesb[i] = v;
  }

  #pragma unroll 1
  for (int iter = 0; iter < 2; ++iter) {
    const int qi = iter ? (31 - pair) : pair;
    const int q0 = qi << 6;
    const int T  = qi + 1;
    const int mid = (T + 1) >> 1;
    const int t0 = half ? mid : 0;
    const int t1 = half ? T : mid;

    floatx4 of[4] = {};
    floatx4 ofl = {};
    float m[4];
    #pragma unroll
    for (int r = 0; r < 4; ++r) m[r] = -1e30f;

    if (t0 < t1) {
      __syncthreads();
      {
        const u16* qp = qkv + base + (size_t)(q0 + prow) * 3072 + qoff + scol;
        *(usx8*)&Ks[prow][scol]     = *(const usx8*)qp;
        *(usx8*)&Ks[prow][scol + 8] = *(const usx8*)(qp + 8);
      }
      __syncthreads();
      const short8 qf0 = *(const short8*)&Ks[wave*16 + l16][quad*8];
      const short8 qf1 = *(const short8*)&Ks[wave*16 + l16][32 + quad*8];

      usx8 kr0, kr1, vr0, vr1;
      {
        const int k0 = t0 << 6;
        const u16* kp = qkv + base + (size_t)(k0 + kmap) * 3072 + koff + scol;
        kr0 = *(const usx8*)kp; kr1 = *(const usx8*)(kp + 8);
        const u16* vp = qkv + base + (size_t)(k0 + 2*kpair) * 3072 + voff + vchunk*8;
        vr0 = *(const usx8*)vp; vr1 = *(const usx8*)(vp + 3072);
      }

      for (int tIdx = t0; tIdx < t1; ++tIdx) {
        __syncthreads();
        *(usx8*)&Ks[prow][scol]     = kr0;
        *(usx8*)&Ks[prow][scol + 8] = kr1;
        #pragma unroll
        for (int i = 0; i < 8; ++i)
          *(unsigned*)&Vt[vchunk*8 + i][2*kpair] =
              (unsigned)vr0[i] | ((unsigned)vr1[i] << 16);
        __syncthreads();

        if (tIdx + 1 < t1) {
          const int kn = (tIdx + 1) << 6;
          const u16* kp = qkv + base + (size_t)(kn + kmap) * 3072 + koff + scol;
          kr0 = *(const usx8*)kp; kr1 = *(const usx8*)(kp + 8);
          const u16* vp = qkv + base + (size_t)(kn + 2*kpair) * 3072 + voff + vchunk*8;
          vr0 = *(const usx8*)vp; vr1 = *(const usx8*)(vp + 3072);
        }

        const int k0 = tIdx << 6;
        floatx4 sf[4];
        #pragma unroll
        for (int kt = 0; kt < 4; ++kt) {
          short8 kf0 = *(const short8*)&Ks[kt*16 + l16][quad*8];
          short8 kf1 = *(const short8*)&Ks[kt*16 + l16][32 + quad*8];
          floatx4 z = {};
          z      = __builtin_amdgcn_mfma_f32_16x16x32_bf16(qf0, kf0, z, 0, 0, 0);
          sf[kt] = __builtin_amdgcn_mfma_f32_16x16x32_bf16(qf1, kf1, z, 0, 0, 0);
        }

        const bool diag = (tIdx == qi);
        #pragma unroll
        for (int r = 0; r < 4; ++r) {
          float sv0 = sf[0][r], sv1 = sf[1][r], sv2 = sf[2][r], sv3 = sf[3][r];
          if (diag) {
            const int qrow = q0 + wave*16 + quad*4 + r;
            const int kbase = k0 + 4*l16;
            if (kbase     > qrow) sv0 = -1e30f;
            if (kbase + 1 > qrow) sv1 = -1e30f;
            if (kbase + 2 > qrow) sv2 = -1e30f;
            if (kbase + 3 > qrow) sv3 = -1e30f;
          }
          float mx = fmaxf(fmaxf(sv0, sv1), fmaxf(sv2, sv3));
          mx = rowmax16(mx);
          const float nm = fmaxf(m[r], mx);
          const float alpha = __builtin_amdgcn_exp2f(m[r] - nm);
          m[r] = nm;
          const float p0 = __builtin_amdgcn_exp2f(sv0 - nm);
          const float p1 = __builtin_amdgcn_exp2f(sv1 - nm);
          const float p2 = __builtin_amdgcn_exp2f(sv2 - nm);
          const float p3 = __builtin_amdgcn_exp2f(sv3 - nm);
          uintx2 pw = { cvt_pk_bf16(p0, p1), cvt_pk_bf16(p2, p3) };
          *(uintx2*)&Ps[wave*16 + quad*4 + r][l16 * 4] = pw;
          #pragma unroll
          for (int dht = 0; dht < 4; ++dht) of[dht][r] *= alpha;
          ofl[r] *= alpha;
        }

        short8 pf0 = *(const short8*)&Ps[wave*16 + l16][quad*8];
        short8 pf1 = *(const short8*)&Ps[wave*16 + l16][32 + quad*8];
        #pragma unroll
        for (int dht = 0; dht < 4; ++dht) {
          short8 vf0 = *(const short8*)&Vt[dht*16 + l16][quad*8];
          short8 vf1 = *(const short8*)&Vt[dht*16 + l16][32 + quad*8];
          of[dht] = __builtin_amdgcn_mfma_f32_16x16x32_bf16(pf0, vf0, of[dht], 0, 0, 0);
          of[dht] = __builtin_amdgcn_mfma_f32_16x16x32_bf16(pf1, vf1, of[dht], 0, 0, 0);
        }
        ofl = __builtin_amdgcn_mfma_f32_16x16x32_bf16(pf0, onesb, ofl, 0, 0, 0);
        ofl = __builtin_amdgcn_mfma_f32_16x16x32_bf16(pf1, onesb, ofl, 0, 0, 0);
      }
    }

    #pragma unroll
    for (int r = 0; r < 4; ++r) {
      const int s = q0 + wave*16 + quad*4 + r;
      u16* orow = opart + obase + (size_t)s * 64;
      #pragma unroll
      for (int dht = 0; dht < 4; ++dht) orow[dht*16 + l16] = f2b(of[dht][r]);
      const float lr = __shfl(ofl[r], quad * 16);
      if (l16 == 0) { ml[mlbase + 2*s] = m[r]; ml[mlbase + 2*s + 1] = lr; }
    }
  }
}

// ---------- combine attention partials -> attnb bf16 [B,S,1024] ----------
__global__ __launch_bounds__(256) void attn_combine_kernel(
    const u16* __restrict__ opart, const float* __restrict__ ml,
    u16* __restrict__ out)
{
  const int t = threadIdx.x;
  const int s = blockIdx.x * 4 + (t >> 6);
  const int lane = t & 63;
  const int h = blockIdx.y, b = blockIdx.z;

  const size_t o0  = ((((size_t)0 * 2 + b) * 16 + h) * 2048 + s) * 64 + lane;
  const size_t o1  = ((((size_t)1 * 2 + b) * 16 + h) * 2048 + s) * 64 + lane;
  const size_t ml0 = ((((size_t)0 * 2 + b) * 16 + h) * 2048 + s) * 2;
  const size_t ml1 = ((((size_t)1 * 2 + b) * 16 + h) * 2048 + s) * 2;

  const float m0 = ml[ml0], l0 = ml[ml0 + 1];
  const float m1 = ml[ml1], l1 = ml[ml1 + 1];
  const float M  = fmaxf(m0, m1);
  const float w0 = __builtin_amdgcn_exp2f(m0 - M);
  const float w1 = __builtin_amdgcn_exp2f(m1 - M);
  const float L  = w0 * l0 + w1 * l1;
  const float o  = w0 * b2f(opart[o0]) + w1 * b2f(opart[o1]);
  out[((size_t)b * 2048 + s) * 1024 + h * 64 + lane] = f2b(o / L);
}

// ---------- K-split combine: out(fp32) = res + sum(p[z]) + bias ----------
template<int NP>
__global__ __launch_bounds__(256) void ksplit_combine_kernel(
    const u16* __restrict__ pp, size_t pstride,
    const float* __restrict__ res, const float* __restrict__ bias,
    float* __restrict__ out)
{
  const size_t i0 = ((size_t)blockIdx.x * 256 + threadIdx.x) * 8;
  usx8 a[NP];
  #pragma unroll
  for (int z = 0; z < NP; ++z) a[z] = *(const usx8*)(pp + z * pstride + i0);
  const int col = (int)(i0 & 1023);
  floatx4 bv0 = *(const floatx4*)(bias + col);
  floatx4 bv1 = *(const floatx4*)(bias + col + 4);
  floatx4 h0 = *(const floatx4*)(res + i0);
  floatx4 h1 = *(const floatx4*)(res + i0 + 4);
  floatx4 o0, o1;
  #pragma unroll
  for (int i = 0; i < 4; ++i) {
    float s0 = h0[i] + bv0[i], s1 = h1[i] + bv1[i];
    #pragma unroll
    for (int z = 0; z < NP; ++z) { s0 += b2f(a[z][i]); s1 += b2f(a[z][4+i]); }
    o0[i] = s0; o1[i] = s1;
  }
  *(floatx4*)(out + i0)     = o0;
  *(floatx4*)(out + i0 + 4) = o1;
}

// ---------- launch ----------
extern "C" void kernel_launch(void* const* d_in, const int* in_sizes, int n_in,
                              void* d_out, int out_size, void* d_ws, size_t ws_size,
                              hipStream_t stream) {
  const float* hidden    = (const float*)d_in[0];
  const float* w_attn    = (const float*)d_in[1];
  const float* b_attn    = (const float*)d_in[2];
  const float* w_proj    = (const float*)d_in[3];
  const float* b_proj    = (const float*)d_in[4];
  const float* w_fc      = (const float*)d_in[5];
  const float* b_fc      = (const float*)d_in[6];
  const float* w_fc_proj = (const float*)d_in[7];
  const float* b_fc_proj = (const float*)d_in[8];
  const float* ln1_w     = (const float*)d_in[9];
  const float* ln1_b     = (const float*)d_in[10];
  const float* ln2_w     = (const float*)d_in[11];
  const float* ln2_b     = (const float*)d_in[12];

  // Workspace layout (MB offsets) — round-5 verified layout
  char* wsb = (char*)d_ws;
  u16*   qkvb  = (u16*)  (wsb + (size_t)( 0u << 20));  // 24 MB [4096,3072]
  u16*   xb    = (u16*)  (wsb + (size_t)(24u << 20));  //  8 MB [4096,1024]
  u16*   opart = (u16*)  (wsb + (size_t)(24u << 20));  // 16 MB (xb dead)
  float* mlbuf = (float*)(wsb + (size_t)(40u << 20));  //  2 MB
  u16*   attnb = (u16*)  (wsb + (size_t)(42u << 20));  //  8 MB [4096,1024]
  u16*   wqT   = (u16*)  (wsb + (size_t)(50u << 20));  //  6 MB [3072,1024]
  u16*   wpT   = (u16*)  (wsb + (size_t)(56u << 20));  //  2 MB [1024,1024]
  u16*   wfT   = (u16*)  (wsb + (size_t)(58u << 20));  //  8 MB [4096,1024]
  u16*   wfpT  = (u16*)  (wsb + (size_t)(66u << 20));  //  8 MB [1024,4096]
  u16*   pproj = (u16*)  (wsb + (size_t)(24u << 20));  // 16 MB (opart dead)
  float* hbuf  = (float*)(wsb + (size_t)(42u << 20));  // 16 MB fp32
  u16*   yb    = (u16*)  (wsb + (size_t)( 0u << 20));  //  8 MB (qkvb dead)
  u16*   fcb   = (u16*)  (wsb + (size_t)( 8u << 20));  // 32 MB
  u16*   p4    = (u16*)  (wsb + (size_t)(74u << 20));  // BIG: 4x8MB partials
  u16*   pfcp0 = (u16*)  (wsb + (size_t)( 0u << 20));  // fallback z0
  const size_t zstr8  = ((size_t)8u << 20) / 2;        // 8 MB in u16 elems
  const size_t zstr58 = ((size_t)58u << 20) / 2;       // fallback stride

  const bool big = ws_size >= ((size_t)106u << 20);

  // 0) weight transpose+convert
  wtrans4_kernel<<<dim3(12288), 256, 0, stream>>>(
      w_attn, w_proj, w_fc, w_fc_proj, wqT, wpT, wfT, wfpT);

  // 1) x = LN1(hidden) -> bf16
  ln_bf16_kernel<<<4096, 256, 0, stream>>>(hidden, ln1_w, ln1_b, xb);
  // 2) qkv = x @ w_attn + b_attn -> bf16; q pre-scaled (flag 8)
  //    128^2 2-phase engine: 768 blocks (full GPU) — verified round 5
  gemm_mfma_kernel<128,128,12,4, 24,32,1, 2,4,1><<<dim3(24, 32, 1), 256, 0, stream>>>(
      xb, wqT, b_attn, nullptr, qkvb, 4096, 3072, 1024, 1024, 0);
  // 3) flash attention partials + combine (verified)
  attn_mfma_kernel<<<dim3(32, 16, 2), 256, 0, stream>>>(qkvb, opart, mlbuf);
  attn_combine_kernel<<<dim3(512, 16, 2), 256, 0, stream>>>(opart, mlbuf, attnb);

  if (big) {
    // 4) proj partials: 256^2 8-phase, K-split x4; 256 blocks; NT=4
    gemm256_kernel<4, 4,16,4, 1,2,4><<<dim3(4, 16, 4), 512, 0, stream>>>(
        attnb, wpT, nullptr, p4, 4096, 1024, 1024, 256, zstr8);
    combine_ln_kernel<4><<<4096, 256, 0, stream>>>(
        p4, zstr8, hidden, b_proj, ln2_w, ln2_b, hbuf, yb);
  } else {
    gemm256_kernel<4, 4,16,2, 1,4,2><<<dim3(4, 16, 2), 512, 0, stream>>>(
        attnb, wpT, nullptr, pproj, 4096, 1024, 1024, 512, zstr8);
    combine_ln_kernel<2><<<4096, 256, 0, stream>>>(
        pproj, zstr8, hidden, b_proj, ln2_w, ln2_b, hbuf, yb);
  }
  // 6) fc = gelu(y @ w_fc + b_fc); 256 blocks (perfect CU fit); NT=16
  gemm256_kernel<5, 16,16,1, 2,4,1><<<dim3(16, 16, 1), 512, 0, stream>>>(
      yb, wfT, b_fc, fcb, 4096, 4096, 1024, 1024, 0);
  if (big) {
    // 7) fc_proj partials: 256^2 8-phase, K-split x4; 256 blocks; NT=16
    gemm256_kernel<4, 4,16,4, 1,2,4><<<dim3(4, 16, 4), 512, 0, stream>>>(
        fcb, wfpT, nullptr, p4, 4096, 1024, 4096, 1024, zstr8);
    ksplit_combine_kernel<4><<<dim3(2048), 256, 0, stream>>>(
        p4, zstr8, hbuf, b_fc_proj, (float*)d_out);
  } else {
    gemm256_kernel<4, 4,16,2, 1,4,2><<<dim3(4, 16, 2), 512, 0, stream>>>(
        fcb, wfpT, nullptr, pfcp0, 4096, 1024, 4096, 2048, zstr58);
    ksplit_combine_kernel<2><<<dim3(2048), 256, 0, stream>>>(
        pfcp0, zstr58, hbuf, b_fc_proj, (float*)d_out);
  }
}

// Round 8
// 346.823 us; speedup vs baseline: 1.2341x; 1.2341x over previous
//
#include <hip/hip_runtime.h>
#include <cstdint>
#include <cstddef>

// ---------- types ----------
typedef unsigned short u16;
typedef float  floatx4 __attribute__((ext_vector_type(4)));
typedef short  short8  __attribute__((ext_vector_type(8)));
typedef u16    usx4    __attribute__((ext_vector_type(4)));
typedef u16    usx8    __attribute__((ext_vector_type(8)));
typedef unsigned uintx2 __attribute__((ext_vector_type(2)));

// fp32 -> bf16, round-to-nearest-even
__device__ __forceinline__ u16 f2b(float f) {
  unsigned u = __float_as_uint(f);
  unsigned r = u + 0x7fffu + ((u >> 16) & 1u);
  return (u16)(r >> 16);
}
__device__ __forceinline__ float b2f(u16 s) {
  return __uint_as_float(((unsigned)s) << 16);
}

// packed fp32x2 -> bf16x2 (hardware RNE); no builtin on gfx950 -> inline asm
__device__ __forceinline__ unsigned cvt_pk_bf16(float lo, float hi) {
  unsigned r;
  asm("v_cvt_pk_bf16_f32 %0, %1, %2" : "=v"(r) : "v"(lo), "v"(hi));
  return r;
}

// max across each 16-lane row via DPP (VALU-only)
__device__ __forceinline__ float rowmax16(float x) {
  int xi = __float_as_int(x), y;
  y = __builtin_amdgcn_update_dpp(xi, xi, 0xB1, 0xF, 0xF, false);  // quad_perm xor1
  x = fmaxf(x, __int_as_float(y)); xi = __float_as_int(x);
  y = __builtin_amdgcn_update_dpp(xi, xi, 0x4E, 0xF, 0xF, false);  // quad_perm xor2
  x = fmaxf(x, __int_as_float(y)); xi = __float_as_int(x);
  y = __builtin_amdgcn_update_dpp(xi, xi, 0x141, 0xF, 0xF, false); // row_half_mirror
  x = fmaxf(x, __int_as_float(y)); xi = __float_as_int(x);
  y = __builtin_amdgcn_update_dpp(xi, xi, 0x140, 0xF, 0xF, false); // row_mirror
  x = fmaxf(x, __int_as_float(y));
  return x;
}

// GPT-2 tanh-gelu, exact algebraic rewrite: 0.5x(1+tanh(u)) = x*sigmoid(2u)
__device__ __forceinline__ float gelu_f(float x) {
  const float k = 2.3022082f;  // 2*sqrt(2/pi)*log2(e)
  float u = x * (1.0f + 0.044715f * x * x);
  float t = __builtin_amdgcn_exp2f(-k * u);
  return x * __builtin_amdgcn_rcpf(1.0f + t);
}

// async global->LDS 16B: lds dst = wave-uniform base + lane*16 (HW rule)
__device__ __forceinline__ void gl2lds16(const u16* g, u16* l) {
  __builtin_amdgcn_global_load_lds(
      (const __attribute__((address_space(1))) unsigned int*)g,
      (__attribute__((address_space(3))) unsigned int*)l, 16, 0, 0);
}

// counted vmcnt wait + raw barrier (T4: younger loads stay in flight)
template<int N> __device__ __forceinline__ void wait_stage_barrier() {
  asm volatile("s_waitcnt vmcnt(%0)" :: "n"(N) : "memory");
  __builtin_amdgcn_s_barrier();
  __builtin_amdgcn_sched_barrier(0);
}
// raw barrier after compute, before re-staging the freed buffer
__device__ __forceinline__ void post_barrier() {
  __builtin_amdgcn_sched_barrier(0);
  __builtin_amdgcn_s_barrier();
  __builtin_amdgcn_sched_barrier(0);
}

#define C2SCALE 0.18033688011112042f  // (1/8) * log2(e)

// ---------- LayerNorm: one block per row of 1024, bf16 out ----------
__global__ __launch_bounds__(256) void ln_bf16_kernel(
    const float* __restrict__ in, const float* __restrict__ w,
    const float* __restrict__ b, u16* __restrict__ out)
{
  const int row = blockIdx.x;
  const int t = threadIdx.x;
  const float* p = in + (size_t)row * 1024 + t * 4;
  floatx4 v = *(const floatx4*)p;
  float s  = v.x + v.y + v.z + v.w;
  float ss = v.x*v.x + v.y*v.y + v.z*v.z + v.w*v.w;
  #pragma unroll
  for (int m = 1; m < 64; m <<= 1) {
    s  += __shfl_xor(s,  m);
    ss += __shfl_xor(ss, m);
  }
  __shared__ float red[8];
  if ((t & 63) == 0) { red[(t >> 6)*2] = s; red[(t >> 6)*2 + 1] = ss; }
  __syncthreads();
  s  = red[0] + red[2] + red[4] + red[6];
  ss = red[1] + red[3] + red[5] + red[7];
  const float mean = s * (1.0f / 1024.0f);
  const float var  = ss * (1.0f / 1024.0f) - mean * mean;
  const float rstd = rsqrtf(var + 1e-6f);
  floatx4 wv = *(const floatx4*)(w + t * 4);
  floatx4 bv = *(const floatx4*)(b + t * 4);
  usx4 o = { f2b(wv.x * ((v.x - mean) * rstd) + bv.x),
             f2b(wv.y * ((v.y - mean) * rstd) + bv.y),
             f2b(wv.z * ((v.z - mean) * rstd) + bv.z),
             f2b(wv.w * ((v.w - mean) * rstd) + bv.w) };
  *(usx4*)(out + (size_t)row * 1024 + t * 4) = o;
}

// ---------- fused K-split combine + LayerNorm (NP partials) ----------
template<int NP>
__global__ __launch_bounds__(256) void combine_ln_kernel(
    const u16* __restrict__ pp, size_t pstride,
    const float* __restrict__ res, const float* __restrict__ bias,
    const float* __restrict__ w, const float* __restrict__ b,
    float* __restrict__ hout, u16* __restrict__ yout)
{
  const int row = blockIdx.x;
  const int t = threadIdx.x;
  const size_t i0 = (size_t)row * 1024 + t * 4;
  floatx4 rv = *(const floatx4*)(res + i0);
  usx4 a[NP];
  #pragma unroll
  for (int z = 0; z < NP; ++z) a[z] = *(const usx4*)(pp + z * pstride + i0);
  floatx4 biasv = *(const floatx4*)(bias + t * 4);
  floatx4 v;
  #pragma unroll
  for (int i = 0; i < 4; ++i) {
    float acc = rv[i] + biasv[i];
    #pragma unroll
    for (int z = 0; z < NP; ++z) acc += b2f(a[z][i]);
    v[i] = acc;
  }
  *(floatx4*)(hout + i0) = v;

  float s  = v.x + v.y + v.z + v.w;
  float ss = v.x*v.x + v.y*v.y + v.z*v.z + v.w*v.w;
  #pragma unroll
  for (int m = 1; m < 64; m <<= 1) {
    s  += __shfl_xor(s,  m);
    ss += __shfl_xor(ss, m);
  }
  __shared__ float red[8];
  if ((t & 63) == 0) { red[(t >> 6)*2] = s; red[(t >> 6)*2 + 1] = ss; }
  __syncthreads();
  s  = red[0] + red[2] + red[4] + red[6];
  ss = red[1] + red[3] + red[5] + red[7];
  const float mean = s * (1.0f / 1024.0f);
  const float var  = ss * (1.0f / 1024.0f) - mean * mean;
  const float rstd = rsqrtf(var + 1e-6f);
  floatx4 wv = *(const floatx4*)(w + t * 4);
  floatx4 bv = *(const floatx4*)(b + t * 4);
  usx4 o = { f2b(wv.x * ((v.x - mean) * rstd) + bv.x),
             f2b(wv.y * ((v.y - mean) * rstd) + bv.y),
             f2b(wv.z * ((v.z - mean) * rstd) + bv.z),
             f2b(wv.w * ((v.w - mean) * rstd) + bv.w) };
  *(usx4*)(yout + i0) = o;
}

// ---------- weight transpose+convert: 4 weights in one launch ----------
__device__ __forceinline__ void wtrans_body(
    const float* __restrict__ in, u16* __restrict__ out, int K, int N,
    int bx, int by, int tx, int ty)
{
  __shared__ u16 tile[32][33];
  const int n0 = bx * 32, k0 = by * 32;
  #pragma unroll
  for (int i = 0; i < 4; ++i)
    tile[ty + i*8][tx] = f2b(in[(size_t)(k0 + ty + i*8) * N + n0 + tx]);
  __syncthreads();
  #pragma unroll
  for (int i = 0; i < 4; ++i)
    out[(size_t)(n0 + ty + i*8) * K + k0 + tx] = tile[tx][ty + i*8];
}

__global__ __launch_bounds__(256) void wtrans4_kernel(
    const float* __restrict__ w0, const float* __restrict__ w1,
    const float* __restrict__ w2, const float* __restrict__ w3,
    u16* __restrict__ o0, u16* __restrict__ o1,
    u16* __restrict__ o2, u16* __restrict__ o3)
{
  int blk = blockIdx.x;
  const int tx = threadIdx.x & 31, ty = threadIdx.x >> 5;
  if (blk < 3072) {
    wtrans_body(w0, o0, 1024, 3072, blk % 96, blk / 96, tx, ty);
  } else if (blk < 4096) {
    blk -= 3072; wtrans_body(w1, o1, 1024, 1024, blk % 32, blk / 32, tx, ty);
  } else if (blk < 8192) {
    blk -= 4096; wtrans_body(w2, o2, 1024, 4096, blk % 128, blk / 128, tx, ty);
  } else {
    blk -= 8192; wtrans_body(w3, o3, 4096, 1024, blk % 32, blk / 32, tx, ty);
  }
}

// ---------- GEMM: C[M,N] = A[M,K] @ Bt[N,K]^T ----------
// m97 tile + T4 counted-vmcnt pipeline at 2 LDS buffers (round-3 verified):
//   phase ti: s_waitcnt vmcnt(L) -> s_barrier -> compute(buf) -> s_barrier
//             -> stage(ti+2 into buf)
// FLAGS: 1 = gelu, 2 = +Res (fp32), 4 = bf16 out, 8 = scale cols<1024 by C2
template<int BM, int BN, int FLAGS, int MINW,
         int NX, int NY, int NZ, int RX, int RY, int RZ>
__global__ __launch_bounds__(256, MINW) void gemm_mfma_kernel(
    const u16* __restrict__ A, const u16* __restrict__ Bt,
    const float* __restrict__ bias, const float* __restrict__ Res,
    void* __restrict__ Cout, int M, int N, int K, int kLen, size_t zStride)
{
  constexpr int WM = BM / 2, WN = BN / 2;
  constexpr int MT = WM / 16, NT = WN / 16;
  constexpr int GX = NX / RX, GY = NY / RY, GZ = NZ / RZ;
  constexpr int ABUF = BM * 32, BBUF = BN * 32;
  constexpr int L = BM / 64 + BN / 64;
  __shared__ u16 As[2 * ABUF];
  __shared__ u16 Bs[2 * BBUF];

  const int lin = blockIdx.x + NX * (blockIdx.y + NY * blockIdx.z);
  const int xcd = lin & 7;
  const int idx = lin >> 3;
  const int rx = xcd % RX, ry = (xcd / RX) % RY, rz = xcd / (RX * RY);
  const int bx = rx * GX + idx % GX;
  const int by = ry * GY + (idx / GX) % GY;
  const int bz = rz * GZ + idx / (GX * GY);

  const int t = threadIdx.x;
  const int wave = t >> 6, lane = t & 63;
  const int quad = lane >> 4, l16 = lane & 15;
  const int wm = wave >> 1, wn = wave & 1;
  const int bm0 = by * BM, bn0 = bx * BN;
  const int kStart = bz * kLen;

  const int sRow = lane >> 2;
  const int sq   = (lane & 3) ^ ((lane >> 4) & 3);

  const u16* aG[BM / 64];
  u16* aL[BM / 64];
  #pragma unroll
  for (int j = 0; j < BM / 64; ++j) {
    const int band = j * 4 + wave;
    aG[j] = A + (size_t)(bm0 + band * 16 + sRow) * K + kStart + sq * 8;
    aL[j] = As + band * 512;
  }
  const u16* bG[BN / 64];
  u16* bL[BN / 64];
  #pragma unroll
  for (int j = 0; j < BN / 64; ++j) {
    const int band = j * 4 + wave;
    bG[j] = Bt + (size_t)(bn0 + band * 16 + sRow) * K + kStart + sq * 8;
    bL[j] = Bs + band * 512;
  }

  floatx4 acc[MT][NT] = {};
  const int rcol = (quad ^ (l16 >> 2)) << 3;

  auto stage = [&](int tile, int buf) {
    #pragma unroll
    for (int j = 0; j < BM / 64; ++j) gl2lds16(aG[j] + tile * 32, aL[j] + buf * ABUF);
    #pragma unroll
    for (int j = 0; j < BN / 64; ++j) gl2lds16(bG[j] + tile * 32, bL[j] + buf * BBUF);
  };
  auto compute = [&](int buf) {
    const u16* Asc = As + buf * ABUF;
    const u16* Bsc = Bs + buf * BBUF;
    short8 af[MT], bf[NT];
    #pragma unroll
    for (int mt = 0; mt < MT; ++mt)
      af[mt] = *(const short8*)&Asc[(wm*WM + mt*16 + l16) * 32 + rcol];
    #pragma unroll
    for (int nt = 0; nt < NT; ++nt)
      bf[nt] = *(const short8*)&Bsc[(wn*WN + nt*16 + l16) * 32 + rcol];
    __builtin_amdgcn_s_setprio(1);
    #pragma unroll
    for (int mt = 0; mt < MT; ++mt)
      #pragma unroll
      for (int nt = 0; nt < NT; ++nt)
        acc[mt][nt] = __builtin_amdgcn_mfma_f32_16x16x32_bf16(af[mt], bf[nt], acc[mt][nt], 0, 0, 0);
    __builtin_amdgcn_s_setprio(0);
  };

  const int nt = kLen >> 5;
  stage(0, 0);
  stage(1, 1);
  #pragma unroll 1
  for (int ti = 0; ti < nt - 2; ti += 2) {
    wait_stage_barrier<L>();
    compute(0);
    post_barrier();
    stage(ti + 2, 0);
    wait_stage_barrier<L>();
    compute(1);
    post_barrier();
    stage(ti + 3, 1);
  }
  wait_stage_barrier<L>();
  compute(0);
  wait_stage_barrier<0>();
  compute(1);

  const int orow0 = bm0 + wm * WM;
  const int ocol0 = bn0 + wn * WN;
  const size_t zoff = (size_t)bz * zStride;
  #pragma unroll
  for (int nt2 = 0; nt2 < NT; ++nt2) {
    const int col = ocol0 + nt2*16 + l16;
    const float bv = bias ? bias[col] : 0.0f;
    const float postscale = ((FLAGS & 8) && col < 1024) ? C2SCALE : 1.0f;
    #pragma unroll
    for (int mt = 0; mt < MT; ++mt) {
      #pragma unroll
      for (int r = 0; r < 4; ++r) {
        const int row = orow0 + mt*16 + quad*4 + r;
        float v = acc[mt][nt2][r] + bv;
        if (FLAGS & 1) v = gelu_f(v);
        if (FLAGS & 8) v *= postscale;
        if (FLAGS & 2) v += Res[(size_t)row * N + col];
        if (FLAGS & 4) ((u16*)Cout)[zoff + (size_t)row * N + col] = f2b(v);
        else           ((float*)Cout)[zoff + (size_t)row * N + col] = v;
      }
    }
  }
}

// ---------- MFMA flash attention (causal), bf16, balanced + K-split ----------
// (round-3/5 verified version)
__global__ __launch_bounds__(256, 4) void attn_mfma_kernel(
    const u16* __restrict__ qkv, u16* __restrict__ opart, float* __restrict__ ml)
{
  __shared__ u16 Ks[64][72];
  __shared__ u16 Vt[64][72];
  __shared__ u16 Ps[64][72];

  const int t    = threadIdx.x;
  const int wave = t >> 6;
  const int lane = t & 63;
  const int quad = lane >> 4;
  const int l16  = lane & 15;
  const int pair = blockIdx.x >> 1;
  const int half = blockIdx.x & 1;
  const int h    = blockIdx.y;
  const int b    = blockIdx.z;

  const size_t base = (size_t)b * 2048 * 3072;
  const int qoff = h * 64;
  const int koff = 1024 + h * 64;
  const int voff = 2048 + h * 64;

  const int prow = t >> 2;
  const int scol = (t & 3) * 16;
  const int kmap = ((prow & 15) << 2) | (prow >> 4);
  const int kpair  = t & 31;
  const int vchunk = t >> 5;

  const size_t obase  = ((((size_t)half * 2 + b) * 16 + h) * 2048) * 64;
  const size_t mlbase = ((((size_t)half * 2 + b) * 16 + h) * 2048) * 2;

  short8 onesb;
  {
    const short v = (l16 == 0) ? (short)0x3F80 : (short)0;
    #pragma unroll
    for (int i = 0; i < 8; ++i) onesb[i] = v;
  }

  #pragma unroll 1
  for (int iter = 0; iter < 2; ++iter) {
    const int qi = iter ? (31 - pair) : pair;
    const int q0 = qi << 6;
    const int T  = qi + 1;
    const int mid = (T + 1) >> 1;
    const int t0 = half ? mid : 0;
    const int t1 = half ? T : mid;

    floatx4 of[4] = {};
    floatx4 ofl = {};
    float m[4];
    #pragma unroll
    for (int r = 0; r < 4; ++r) m[r] = -1e30f;

    if (t0 < t1) {
      __syncthreads();
      {
        const u16* qp = qkv + base + (size_t)(q0 + prow) * 3072 + qoff + scol;
        *(usx8*)&Ks[prow][scol]     = *(const usx8*)qp;
        *(usx8*)&Ks[prow][scol + 8] = *(const usx8*)(qp + 8);
      }
      __syncthreads();
      const short8 qf0 = *(const short8*)&Ks[wave*16 + l16][quad*8];
      const short8 qf1 = *(const short8*)&Ks[wave*16 + l16][32 + quad*8];

      usx8 kr0, kr1, vr0, vr1;
      {
        const int k0 = t0 << 6;
        const u16* kp = qkv + base + (size_t)(k0 + kmap) * 3072 + koff + scol;
        kr0 = *(const usx8*)kp; kr1 = *(const usx8*)(kp + 8);
        const u16* vp = qkv + base + (size_t)(k0 + 2*kpair) * 3072 + voff + vchunk*8;
        vr0 = *(const usx8*)vp; vr1 = *(const usx8*)(vp + 3072);
      }

      for (int tIdx = t0; tIdx < t1; ++tIdx) {
        __syncthreads();
        *(usx8*)&Ks[prow][scol]     = kr0;
        *(usx8*)&Ks[prow][scol + 8] = kr1;
        #pragma unroll
        for (int i = 0; i < 8; ++i)
          *(unsigned*)&Vt[vchunk*8 + i][2*kpair] =
              (unsigned)vr0[i] | ((unsigned)vr1[i] << 16);
        __syncthreads();

        if (tIdx + 1 < t1) {
          const int kn = (tIdx + 1) << 6;
          const u16* kp = qkv + base + (size_t)(kn + kmap) * 3072 + koff + scol;
          kr0 = *(const usx8*)kp; kr1 = *(const usx8*)(kp + 8);
          const u16* vp = qkv + base + (size_t)(kn + 2*kpair) * 3072 + voff + vchunk*8;
          vr0 = *(const usx8*)vp; vr1 = *(const usx8*)(vp + 3072);
        }

        const int k0 = tIdx << 6;
        floatx4 sf[4];
        #pragma unroll
        for (int kt = 0; kt < 4; ++kt) {
          short8 kf0 = *(const short8*)&Ks[kt*16 + l16][quad*8];
          short8 kf1 = *(const short8*)&Ks[kt*16 + l16][32 + quad*8];
          floatx4 z = {};
          z      = __builtin_amdgcn_mfma_f32_16x16x32_bf16(qf0, kf0, z, 0, 0, 0);
          sf[kt] = __builtin_amdgcn_mfma_f32_16x16x32_bf16(qf1, kf1, z, 0, 0, 0);
        }

        const bool diag = (tIdx == qi);
        #pragma unroll
        for (int r = 0; r < 4; ++r) {
          float sv0 = sf[0][r], sv1 = sf[1][r], sv2 = sf[2][r], sv3 = sf[3][r];
          if (diag) {
            const int qrow = q0 + wave*16 + quad*4 + r;
            const int kbase = k0 + 4*l16;
            if (kbase     > qrow) sv0 = -1e30f;
            if (kbase + 1 > qrow) sv1 = -1e30f;
            if (kbase + 2 > qrow) sv2 = -1e30f;
            if (kbase + 3 > qrow) sv3 = -1e30f;
          }
          float mx = fmaxf(fmaxf(sv0, sv1), fmaxf(sv2, sv3));
          mx = rowmax16(mx);
          const float nm = fmaxf(m[r], mx);
          const float alpha = __builtin_amdgcn_exp2f(m[r] - nm);
          m[r] = nm;
          const float p0 = __builtin_amdgcn_exp2f(sv0 - nm);
          const float p1 = __builtin_amdgcn_exp2f(sv1 - nm);
          const float p2 = __builtin_amdgcn_exp2f(sv2 - nm);
          const float p3 = __builtin_amdgcn_exp2f(sv3 - nm);
          uintx2 pw = { cvt_pk_bf16(p0, p1), cvt_pk_bf16(p2, p3) };
          *(uintx2*)&Ps[wave*16 + quad*4 + r][l16 * 4] = pw;
          #pragma unroll
          for (int dht = 0; dht < 4; ++dht) of[dht][r] *= alpha;
          ofl[r] *= alpha;
        }

        short8 pf0 = *(const short8*)&Ps[wave*16 + l16][quad*8];
        short8 pf1 = *(const short8*)&Ps[wave*16 + l16][32 + quad*8];
        #pragma unroll
        for (int dht = 0; dht < 4; ++dht) {
          short8 vf0 = *(const short8*)&Vt[dht*16 + l16][quad*8];
          short8 vf1 = *(const short8*)&Vt[dht*16 + l16][32 + quad*8];
          of[dht] = __builtin_amdgcn_mfma_f32_16x16x32_bf16(pf0, vf0, of[dht], 0, 0, 0);
          of[dht] = __builtin_amdgcn_mfma_f32_16x16x32_bf16(pf1, vf1, of[dht], 0, 0, 0);
        }
        ofl = __builtin_amdgcn_mfma_f32_16x16x32_bf16(pf0, onesb, ofl, 0, 0, 0);
        ofl = __builtin_amdgcn_mfma_f32_16x16x32_bf16(pf1, onesb, ofl, 0, 0, 0);
      }
    }

    #pragma unroll
    for (int r = 0; r < 4; ++r) {
      const int s = q0 + wave*16 + quad*4 + r;
      u16* orow = opart + obase + (size_t)s * 64;
      #pragma unroll
      for (int dht = 0; dht < 4; ++dht) orow[dht*16 + l16] = f2b(of[dht][r]);
      const float lr = __shfl(ofl[r], quad * 16);
      if (l16 == 0) { ml[mlbase + 2*s] = m[r]; ml[mlbase + 2*s + 1] = lr; }
    }
  }
}

// ---------- combine attention partials -> attnb bf16 [B,S,1024] ----------
__global__ __launch_bounds__(256) void attn_combine_kernel(
    const u16* __restrict__ opart, const float* __restrict__ ml,
    u16* __restrict__ out)
{
  const int t = threadIdx.x;
  const int s = blockIdx.x * 4 + (t >> 6);
  const int lane = t & 63;
  const int h = blockIdx.y, b = blockIdx.z;

  const size_t o0  = ((((size_t)0 * 2 + b) * 16 + h) * 2048 + s) * 64 + lane;
  const size_t o1  = ((((size_t)1 * 2 + b) * 16 + h) * 2048 + s) * 64 + lane;
  const size_t ml0 = ((((size_t)0 * 2 + b) * 16 + h) * 2048 + s) * 2;
  const size_t ml1 = ((((size_t)1 * 2 + b) * 16 + h) * 2048 + s) * 2;

  const float m0 = ml[ml0], l0 = ml[ml0 + 1];
  const float m1 = ml[ml1], l1 = ml[ml1 + 1];
  const float M  = fmaxf(m0, m1);
  const float w0 = __builtin_amdgcn_exp2f(m0 - M);
  const float w1 = __builtin_amdgcn_exp2f(m1 - M);
  const float L  = w0 * l0 + w1 * l1;
  const float o  = w0 * b2f(opart[o0]) + w1 * b2f(opart[o1]);
  out[((size_t)b * 2048 + s) * 1024 + h * 64 + lane] = f2b(o / L);
}

// ---------- K-split combine: out(fp32) = res + sum(p[z]) + bias ----------
template<int NP>
__global__ __launch_bounds__(256) void ksplit_combine_kernel(
    const u16* __restrict__ pp, size_t pstride,
    const float* __restrict__ res, const float* __restrict__ bias,
    float* __restrict__ out)
{
  const size_t i0 = ((size_t)blockIdx.x * 256 + threadIdx.x) * 8;
  usx8 a[NP];
  #pragma unroll
  for (int z = 0; z < NP; ++z) a[z] = *(const usx8*)(pp + z * pstride + i0);
  const int col = (int)(i0 & 1023);
  floatx4 bv0 = *(const floatx4*)(bias + col);
  floatx4 bv1 = *(const floatx4*)(bias + col + 4);
  floatx4 h0 = *(const floatx4*)(res + i0);
  floatx4 h1 = *(const floatx4*)(res + i0 + 4);
  floatx4 o0, o1;
  #pragma unroll
  for (int i = 0; i < 4; ++i) {
    float s0 = h0[i] + bv0[i], s1 = h1[i] + bv1[i];
    #pragma unroll
    for (int z = 0; z < NP; ++z) { s0 += b2f(a[z][i]); s1 += b2f(a[z][4+i]); }
    o0[i] = s0; o1[i] = s1;
  }
  *(floatx4*)(out + i0)     = o0;
  *(floatx4*)(out + i0 + 4) = o1;
}

// ---------- launch ----------
extern "C" void kernel_launch(void* const* d_in, const int* in_sizes, int n_in,
                              void* d_out, int out_size, void* d_ws, size_t ws_size,
                              hipStream_t stream) {
  const float* hidden    = (const float*)d_in[0];
  const float* w_attn    = (const float*)d_in[1];
  const float* b_attn    = (const float*)d_in[2];
  const float* w_proj    = (const float*)d_in[3];
  const float* b_proj    = (const float*)d_in[4];
  const float* w_fc      = (const float*)d_in[5];
  const float* b_fc      = (const float*)d_in[6];
  const float* w_fc_proj = (const float*)d_in[7];
  const float* b_fc_proj = (const float*)d_in[8];
  const float* ln1_w     = (const float*)d_in[9];
  const float* ln1_b     = (const float*)d_in[10];
  const float* ln2_w     = (const float*)d_in[11];
  const float* ln2_b     = (const float*)d_in[12];

  // Workspace layout (MB offsets) — round-5 verified layout
  char* wsb = (char*)d_ws;
  u16*   qkvb  = (u16*)  (wsb + (size_t)( 0u << 20));  // 24 MB [4096,3072]
  u16*   xb    = (u16*)  (wsb + (size_t)(24u << 20));  //  8 MB [4096,1024]
  u16*   opart = (u16*)  (wsb + (size_t)(24u << 20));  // 16 MB (xb dead)
  float* mlbuf = (float*)(wsb + (size_t)(40u << 20));  //  2 MB
  u16*   attnb = (u16*)  (wsb + (size_t)(42u << 20));  //  8 MB [4096,1024]
  u16*   wqT   = (u16*)  (wsb + (size_t)(50u << 20));  //  6 MB [3072,1024]
  u16*   wpT   = (u16*)  (wsb + (size_t)(56u << 20));  //  2 MB [1024,1024]
  u16*   wfT   = (u16*)  (wsb + (size_t)(58u << 20));  //  8 MB [4096,1024]
  u16*   wfpT  = (u16*)  (wsb + (size_t)(66u << 20));  //  8 MB [1024,4096]
  u16*   pproj = (u16*)  (wsb + (size_t)(24u << 20));  // 16 MB (opart dead)
  float* hbuf  = (float*)(wsb + (size_t)(42u << 20));  // 16 MB fp32
  u16*   yb    = (u16*)  (wsb + (size_t)( 0u << 20));  //  8 MB (qkvb dead)
  u16*   fcb   = (u16*)  (wsb + (size_t)( 8u << 20));  // 32 MB
  u16*   p4    = (u16*)  (wsb + (size_t)(74u << 20));  // BIG: 4x8MB partials
  u16*   pfcp0 = (u16*)  (wsb + (size_t)( 0u << 20));  // fallback z0
  const size_t zstr8  = ((size_t)8u << 20) / 2;        // 8 MB in u16 elems
  const size_t zstr58 = ((size_t)58u << 20) / 2;       // fallback stride

  const bool big = ws_size >= ((size_t)106u << 20);

  // 0) weight transpose+convert
  wtrans4_kernel<<<dim3(12288), 256, 0, stream>>>(
      w_attn, w_proj, w_fc, w_fc_proj, wqT, wpT, wfT, wfpT);

  // 1) x = LN1(hidden) -> bf16
  ln_bf16_kernel<<<4096, 256, 0, stream>>>(hidden, ln1_w, ln1_b, xb);
  // 2) qkv = x @ w_attn + b_attn -> bf16; q pre-scaled (flag 8); 768 blocks
  gemm_mfma_kernel<128,128,12,4, 24,32,1, 2,4,1><<<dim3(24, 32, 1), 256, 0, stream>>>(
      xb, wqT, b_attn, nullptr, qkvb, 4096, 3072, 1024, 1024, 0);
  // 3) flash attention partials + combine (verified)
  attn_mfma_kernel<<<dim3(32, 16, 2), 256, 0, stream>>>(qkvb, opart, mlbuf);
  attn_combine_kernel<<<dim3(512, 16, 2), 256, 0, stream>>>(opart, mlbuf, attnb);

  // 4) proj partials: K-split x2, 128x64 tile (round-3 config — best measured)
  gemm_mfma_kernel<128,64,4,4, 16,32,2, 1,4,2><<<dim3(16, 32, 2), 256, 0, stream>>>(
      attnb, wpT, nullptr, nullptr, pproj, 4096, 1024, 1024, 512, zstr8);
  // 4b+5) h = hidden + p0 + p1 + b_proj; y = LN2(h)
  combine_ln_kernel<2><<<4096, 256, 0, stream>>>(
      pproj, zstr8, hidden, b_proj, ln2_w, ln2_b, hbuf, yb);
  // 6) fc = gelu(y @ w_fc + b_fc); 1024 blocks (round-3 config)
  gemm_mfma_kernel<128,128,5,4, 32,32,1, 2,4,1><<<dim3(32, 32, 1), 256, 0, stream>>>(
      yb, wfT, b_fc, nullptr, fcb, 4096, 4096, 1024, 1024, 0);
  if (big) {
    // 7) fc_proj partials: K-split x4, 128x128 tile (round-5 measured −9 µs)
    gemm_mfma_kernel<128,128,4,4, 8,32,4, 1,2,4><<<dim3(8, 32, 4), 256, 0, stream>>>(
        fcb, wfpT, nullptr, nullptr, p4, 4096, 1024, 4096, 1024, zstr8);
    // 8) out = h + sum(p) + b_fc_proj -> fp32
    ksplit_combine_kernel<4><<<dim3(2048), 256, 0, stream>>>(
        p4, zstr8, hbuf, b_fc_proj, (float*)d_out);
  } else {
    gemm_mfma_kernel<128,64,4,4, 16,32,2, 1,4,2><<<dim3(16, 32, 2), 256, 0, stream>>>(
        fcb, wfpT, nullptr, nullptr, pfcp0, 4096, 1024, 4096, 2048, zstr58);
    ksplit_combine_kernel<2><<<dim3(2048), 256, 0, stream>>>(
        pfcp0, zstr58, hbuf, b_fc_proj, (float*)d_out);
  }
}

// Round 9
// 345.790 us; speedup vs baseline: 1.2378x; 1.0030x over previous
//
#include <hip/hip_runtime.h>
#include <cstdint>
#include <cstddef>

// ---------- types ----------
typedef unsigned short u16;
typedef float  floatx4 __attribute__((ext_vector_type(4)));
typedef short  short8  __attribute__((ext_vector_type(8)));
typedef u16    usx4    __attribute__((ext_vector_type(4)));
typedef u16    usx8    __attribute__((ext_vector_type(8)));
typedef unsigned uintx2 __attribute__((ext_vector_type(2)));

// fp32 -> bf16, round-to-nearest-even
__device__ __forceinline__ u16 f2b(float f) {
  unsigned u = __float_as_uint(f);
  unsigned r = u + 0x7fffu + ((u >> 16) & 1u);
  return (u16)(r >> 16);
}
__device__ __forceinline__ float b2f(u16 s) {
  return __uint_as_float(((unsigned)s) << 16);
}

// packed fp32x2 -> bf16x2 (hardware RNE); no builtin on gfx950 -> inline asm
__device__ __forceinline__ unsigned cvt_pk_bf16(float lo, float hi) {
  unsigned r;
  asm("v_cvt_pk_bf16_f32 %0, %1, %2" : "=v"(r) : "v"(lo), "v"(hi));
  return r;
}

// max across each 16-lane row via DPP (VALU-only)
__device__ __forceinline__ float rowmax16(float x) {
  int xi = __float_as_int(x), y;
  y = __builtin_amdgcn_update_dpp(xi, xi, 0xB1, 0xF, 0xF, false);  // quad_perm xor1
  x = fmaxf(x, __int_as_float(y)); xi = __float_as_int(x);
  y = __builtin_amdgcn_update_dpp(xi, xi, 0x4E, 0xF, 0xF, false);  // quad_perm xor2
  x = fmaxf(x, __int_as_float(y)); xi = __float_as_int(x);
  y = __builtin_amdgcn_update_dpp(xi, xi, 0x141, 0xF, 0xF, false); // row_half_mirror
  x = fmaxf(x, __int_as_float(y)); xi = __float_as_int(x);
  y = __builtin_amdgcn_update_dpp(xi, xi, 0x140, 0xF, 0xF, false); // row_mirror
  x = fmaxf(x, __int_as_float(y));
  return x;
}

// GPT-2 tanh-gelu, exact algebraic rewrite: 0.5x(1+tanh(u)) = x*sigmoid(2u)
__device__ __forceinline__ float gelu_f(float x) {
  const float k = 2.3022082f;  // 2*sqrt(2/pi)*log2(e)
  float u = x * (1.0f + 0.044715f * x * x);
  float t = __builtin_amdgcn_exp2f(-k * u);
  return x * __builtin_amdgcn_rcpf(1.0f + t);
}

// async global->LDS 16B: lds dst = wave-uniform base + lane*16 (HW rule)
__device__ __forceinline__ void gl2lds16(const u16* g, u16* l) {
  __builtin_amdgcn_global_load_lds(
      (const __attribute__((address_space(1))) unsigned int*)g,
      (__attribute__((address_space(3))) unsigned int*)l, 16, 0, 0);
}

// counted vmcnt wait + raw barrier (T4: younger loads stay in flight)
template<int N> __device__ __forceinline__ void wait_stage_barrier() {
  asm volatile("s_waitcnt vmcnt(%0)" :: "n"(N) : "memory");
  __builtin_amdgcn_s_barrier();
  __builtin_amdgcn_sched_barrier(0);
}
// raw barrier after compute, before re-staging the freed buffer
__device__ __forceinline__ void post_barrier() {
  __builtin_amdgcn_sched_barrier(0);
  __builtin_amdgcn_s_barrier();
  __builtin_amdgcn_sched_barrier(0);
}

#define C2SCALE 0.18033688011112042f  // (1/8) * log2(e)

// ---------- LayerNorm: one block per row of 1024, bf16 out ----------
__global__ __launch_bounds__(256) void ln_bf16_kernel(
    const float* __restrict__ in, const float* __restrict__ w,
    const float* __restrict__ b, u16* __restrict__ out)
{
  const int row = blockIdx.x;
  const int t = threadIdx.x;
  const float* p = in + (size_t)row * 1024 + t * 4;
  floatx4 v = *(const floatx4*)p;
  float s  = v.x + v.y + v.z + v.w;
  float ss = v.x*v.x + v.y*v.y + v.z*v.z + v.w*v.w;
  #pragma unroll
  for (int m = 1; m < 64; m <<= 1) {
    s  += __shfl_xor(s,  m);
    ss += __shfl_xor(ss, m);
  }
  __shared__ float red[8];
  if ((t & 63) == 0) { red[(t >> 6)*2] = s; red[(t >> 6)*2 + 1] = ss; }
  __syncthreads();
  s  = red[0] + red[2] + red[4] + red[6];
  ss = red[1] + red[3] + red[5] + red[7];
  const float mean = s * (1.0f / 1024.0f);
  const float var  = ss * (1.0f / 1024.0f) - mean * mean;
  const float rstd = rsqrtf(var + 1e-6f);
  floatx4 wv = *(const floatx4*)(w + t * 4);
  floatx4 bv = *(const floatx4*)(b + t * 4);
  usx4 o = { f2b(wv.x * ((v.x - mean) * rstd) + bv.x),
             f2b(wv.y * ((v.y - mean) * rstd) + bv.y),
             f2b(wv.z * ((v.z - mean) * rstd) + bv.z),
             f2b(wv.w * ((v.w - mean) * rstd) + bv.w) };
  *(usx4*)(out + (size_t)row * 1024 + t * 4) = o;
}

// ---------- fused K-split combine + LayerNorm (NP partials) ----------
template<int NP>
__global__ __launch_bounds__(256) void combine_ln_kernel(
    const u16* __restrict__ pp, size_t pstride,
    const float* __restrict__ res, const float* __restrict__ bias,
    const float* __restrict__ w, const float* __restrict__ b,
    float* __restrict__ hout, u16* __restrict__ yout)
{
  const int row = blockIdx.x;
  const int t = threadIdx.x;
  const size_t i0 = (size_t)row * 1024 + t * 4;
  floatx4 rv = *(const floatx4*)(res + i0);
  usx4 a[NP];
  #pragma unroll
  for (int z = 0; z < NP; ++z) a[z] = *(const usx4*)(pp + z * pstride + i0);
  floatx4 biasv = *(const floatx4*)(bias + t * 4);
  floatx4 v;
  #pragma unroll
  for (int i = 0; i < 4; ++i) {
    float acc = rv[i] + biasv[i];
    #pragma unroll
    for (int z = 0; z < NP; ++z) acc += b2f(a[z][i]);
    v[i] = acc;
  }
  *(floatx4*)(hout + i0) = v;

  float s  = v.x + v.y + v.z + v.w;
  float ss = v.x*v.x + v.y*v.y + v.z*v.z + v.w*v.w;
  #pragma unroll
  for (int m = 1; m < 64; m <<= 1) {
    s  += __shfl_xor(s,  m);
    ss += __shfl_xor(ss, m);
  }
  __shared__ float red[8];
  if ((t & 63) == 0) { red[(t >> 6)*2] = s; red[(t >> 6)*2 + 1] = ss; }
  __syncthreads();
  s  = red[0] + red[2] + red[4] + red[6];
  ss = red[1] + red[3] + red[5] + red[7];
  const float mean = s * (1.0f / 1024.0f);
  const float var  = ss * (1.0f / 1024.0f) - mean * mean;
  const float rstd = rsqrtf(var + 1e-6f);
  floatx4 wv = *(const floatx4*)(w + t * 4);
  floatx4 bv = *(const floatx4*)(b + t * 4);
  usx4 o = { f2b(wv.x * ((v.x - mean) * rstd) + bv.x),
             f2b(wv.y * ((v.y - mean) * rstd) + bv.y),
             f2b(wv.z * ((v.z - mean) * rstd) + bv.z),
             f2b(wv.w * ((v.w - mean) * rstd) + bv.w) };
  *(usx4*)(yout + i0) = o;
}

// ---------- weight transpose+convert: 4 weights in one launch ----------
__device__ __forceinline__ void wtrans_body(
    const float* __restrict__ in, u16* __restrict__ out, int K, int N,
    int bx, int by, int tx, int ty)
{
  __shared__ u16 tile[32][33];
  const int n0 = bx * 32, k0 = by * 32;
  #pragma unroll
  for (int i = 0; i < 4; ++i)
    tile[ty + i*8][tx] = f2b(in[(size_t)(k0 + ty + i*8) * N + n0 + tx]);
  __syncthreads();
  #pragma unroll
  for (int i = 0; i < 4; ++i)
    out[(size_t)(n0 + ty + i*8) * K + k0 + tx] = tile[tx][ty + i*8];
}

__global__ __launch_bounds__(256) void wtrans4_kernel(
    const float* __restrict__ w0, const float* __restrict__ w1,
    const float* __restrict__ w2, const float* __restrict__ w3,
    u16* __restrict__ o0, u16* __restrict__ o1,
    u16* __restrict__ o2, u16* __restrict__ o3)
{
  int blk = blockIdx.x;
  const int tx = threadIdx.x & 31, ty = threadIdx.x >> 5;
  if (blk < 3072) {
    wtrans_body(w0, o0, 1024, 3072, blk % 96, blk / 96, tx, ty);
  } else if (blk < 4096) {
    blk -= 3072; wtrans_body(w1, o1, 1024, 1024, blk % 32, blk / 32, tx, ty);
  } else if (blk < 8192) {
    blk -= 4096; wtrans_body(w2, o2, 1024, 4096, blk % 128, blk / 128, tx, ty);
  } else {
    blk -= 8192; wtrans_body(w3, o3, 4096, 1024, blk % 32, blk / 32, tx, ty);
  }
}

// ---------- GEMM: C[M,N] = A[M,K] @ Bt[N,K]^T ----------
// m97 tile + T4 counted-vmcnt pipeline at 2 LDS buffers (round-3 verified):
//   phase ti: s_waitcnt vmcnt(L) -> s_barrier -> compute(buf) -> s_barrier
//             -> stage(ti+2 into buf)
// FLAGS: 1 = gelu, 2 = +Res (fp32), 4 = bf16 out, 8 = scale cols<1024 by C2
template<int BM, int BN, int FLAGS, int MINW,
         int NX, int NY, int NZ, int RX, int RY, int RZ>
__global__ __launch_bounds__(256, MINW) void gemm_mfma_kernel(
    const u16* __restrict__ A, const u16* __restrict__ Bt,
    const float* __restrict__ bias, const float* __restrict__ Res,
    void* __restrict__ Cout, int M, int N, int K, int kLen, size_t zStride)
{
  constexpr int WM = BM / 2, WN = BN / 2;
  constexpr int MT = WM / 16, NT = WN / 16;
  constexpr int GX = NX / RX, GY = NY / RY, GZ = NZ / RZ;
  constexpr int ABUF = BM * 32, BBUF = BN * 32;
  constexpr int L = BM / 64 + BN / 64;
  __shared__ u16 As[2 * ABUF];
  __shared__ u16 Bs[2 * BBUF];

  const int lin = blockIdx.x + NX * (blockIdx.y + NY * blockIdx.z);
  const int xcd = lin & 7;
  const int idx = lin >> 3;
  const int rx = xcd % RX, ry = (xcd / RX) % RY, rz = xcd / (RX * RY);
  const int bx = rx * GX + idx % GX;
  const int by = ry * GY + (idx / GX) % GY;
  const int bz = rz * GZ + idx / (GX * GY);

  const int t = threadIdx.x;
  const int wave = t >> 6, lane = t & 63;
  const int quad = lane >> 4, l16 = lane & 15;
  const int wm = wave >> 1, wn = wave & 1;
  const int bm0 = by * BM, bn0 = bx * BN;
  const int kStart = bz * kLen;

  const int sRow = lane >> 2;
  const int sq   = (lane & 3) ^ ((lane >> 4) & 3);

  const u16* aG[BM / 64];
  u16* aL[BM / 64];
  #pragma unroll
  for (int j = 0; j < BM / 64; ++j) {
    const int band = j * 4 + wave;
    aG[j] = A + (size_t)(bm0 + band * 16 + sRow) * K + kStart + sq * 8;
    aL[j] = As + band * 512;
  }
  const u16* bG[BN / 64];
  u16* bL[BN / 64];
  #pragma unroll
  for (int j = 0; j < BN / 64; ++j) {
    const int band = j * 4 + wave;
    bG[j] = Bt + (size_t)(bn0 + band * 16 + sRow) * K + kStart + sq * 8;
    bL[j] = Bs + band * 512;
  }

  floatx4 acc[MT][NT] = {};
  const int rcol = (quad ^ (l16 >> 2)) << 3;

  auto stage = [&](int tile, int buf) {
    #pragma unroll
    for (int j = 0; j < BM / 64; ++j) gl2lds16(aG[j] + tile * 32, aL[j] + buf * ABUF);
    #pragma unroll
    for (int j = 0; j < BN / 64; ++j) gl2lds16(bG[j] + tile * 32, bL[j] + buf * BBUF);
  };
  auto compute = [&](int buf) {
    const u16* Asc = As + buf * ABUF;
    const u16* Bsc = Bs + buf * BBUF;
    short8 af[MT], bf[NT];
    #pragma unroll
    for (int mt = 0; mt < MT; ++mt)
      af[mt] = *(const short8*)&Asc[(wm*WM + mt*16 + l16) * 32 + rcol];
    #pragma unroll
    for (int nt = 0; nt < NT; ++nt)
      bf[nt] = *(const short8*)&Bsc[(wn*WN + nt*16 + l16) * 32 + rcol];
    __builtin_amdgcn_s_setprio(1);
    #pragma unroll
    for (int mt = 0; mt < MT; ++mt)
      #pragma unroll
      for (int nt = 0; nt < NT; ++nt)
        acc[mt][nt] = __builtin_amdgcn_mfma_f32_16x16x32_bf16(af[mt], bf[nt], acc[mt][nt], 0, 0, 0);
    __builtin_amdgcn_s_setprio(0);
  };

  const int nt = kLen >> 5;
  stage(0, 0);
  stage(1, 1);
  #pragma unroll 1
  for (int ti = 0; ti < nt - 2; ti += 2) {
    wait_stage_barrier<L>();
    compute(0);
    post_barrier();
    stage(ti + 2, 0);
    wait_stage_barrier<L>();
    compute(1);
    post_barrier();
    stage(ti + 3, 1);
  }
  wait_stage_barrier<L>();
  compute(0);
  wait_stage_barrier<0>();
  compute(1);

  const int orow0 = bm0 + wm * WM;
  const int ocol0 = bn0 + wn * WN;
  const size_t zoff = (size_t)bz * zStride;
  #pragma unroll
  for (int nt2 = 0; nt2 < NT; ++nt2) {
    const int col = ocol0 + nt2*16 + l16;
    const float bv = bias ? bias[col] : 0.0f;
    const float postscale = ((FLAGS & 8) && col < 1024) ? C2SCALE : 1.0f;
    #pragma unroll
    for (int mt = 0; mt < MT; ++mt) {
      #pragma unroll
      for (int r = 0; r < 4; ++r) {
        const int row = orow0 + mt*16 + quad*4 + r;
        float v = acc[mt][nt2][r] + bv;
        if (FLAGS & 1) v = gelu_f(v);
        if (FLAGS & 8) v *= postscale;
        if (FLAGS & 2) v += Res[(size_t)row * N + col];
        if (FLAGS & 4) ((u16*)Cout)[zoff + (size_t)row * N + col] = f2b(v);
        else           ((float*)Cout)[zoff + (size_t)row * N + col] = v;
      }
    }
  }
}

// ---------- MFMA flash attention (causal), bf16, balanced + K-split ----------
// Round-3/5/8 verified compute; NEW: XCD-clustered block remap so all 32
// blocks sharing one (h,b)'s K/V stream land on ONE XCD (lin%8 round-robin
// assumption; bijective; speed-only heuristic, G16-safe). Each XCD serves 4
// (h,b) combos -> 2 MB K/V working set in its 4 MB private L2 instead of
// every XCD refetching all K/V (round-0 FETCH was 94 MB vs ~40 ideal).
__global__ __launch_bounds__(256, 4) void attn_mfma_kernel(
    const u16* __restrict__ qkv, u16* __restrict__ opart, float* __restrict__ ml)
{
  __shared__ u16 Ks[64][72];
  __shared__ u16 Vt[64][72];
  __shared__ u16 Ps[64][72];

  const int t    = threadIdx.x;
  const int wave = t >> 6;
  const int lane = t & 63;
  const int quad = lane >> 4;
  const int l16  = lane & 15;

  // ---- XCD-clustered remap: lin -> (xcd, idx) -> (hb, xr) ----
  const int lin  = blockIdx.x + 32 * (blockIdx.y + 16 * blockIdx.z);
  const int xcd  = lin & 7;
  const int idx  = lin >> 3;            // 0..127
  const int hb   = xcd * 4 + (idx >> 5);// 0..31 (4 (h,b) combos per XCD)
  const int xr   = idx & 31;            // 0..31 within (h,b)
  const int pair = xr >> 1;
  const int half = xr & 1;
  const int h    = hb & 15;
  const int b    = hb >> 4;

  const size_t base = (size_t)b * 2048 * 3072;
  const int qoff = h * 64;
  const int koff = 1024 + h * 64;
  const int voff = 2048 + h * 64;

  const int prow = t >> 2;
  const int scol = (t & 3) * 16;
  const int kmap = ((prow & 15) << 2) | (prow >> 4);
  const int kpair  = t & 31;
  const int vchunk = t >> 5;

  const size_t obase  = ((((size_t)half * 2 + b) * 16 + h) * 2048) * 64;
  const size_t mlbase = ((((size_t)half * 2 + b) * 16 + h) * 2048) * 2;

  short8 onesb;
  {
    const short v = (l16 == 0) ? (short)0x3F80 : (short)0;
    #pragma unroll
    for (int i = 0; i < 8; ++i) onesb[i] = v;
  }

  #pragma unroll 1
  for (int iter = 0; iter < 2; ++iter) {
    const int qi = iter ? (31 - pair) : pair;
    const int q0 = qi << 6;
    const int T  = qi + 1;
    const int mid = (T + 1) >> 1;
    const int t0 = half ? mid : 0;
    const int t1 = half ? T : mid;

    floatx4 of[4] = {};
    floatx4 ofl = {};
    float m[4];
    #pragma unroll
    for (int r = 0; r < 4; ++r) m[r] = -1e30f;

    if (t0 < t1) {
      __syncthreads();
      {
        const u16* qp = qkv + base + (size_t)(q0 + prow) * 3072 + qoff + scol;
        *(usx8*)&Ks[prow][scol]     = *(const usx8*)qp;
        *(usx8*)&Ks[prow][scol + 8] = *(const usx8*)(qp + 8);
      }
      __syncthreads();
      const short8 qf0 = *(const short8*)&Ks[wave*16 + l16][quad*8];
      const short8 qf1 = *(const short8*)&Ks[wave*16 + l16][32 + quad*8];

      usx8 kr0, kr1, vr0, vr1;
      {
        const int k0 = t0 << 6;
        const u16* kp = qkv + base + (size_t)(k0 + kmap) * 3072 + koff + scol;
        kr0 = *(const usx8*)kp; kr1 = *(const usx8*)(kp + 8);
        const u16* vp = qkv + base + (size_t)(k0 + 2*kpair) * 3072 + voff + vchunk*8;
        vr0 = *(const usx8*)vp; vr1 = *(const usx8*)(vp + 3072);
      }

      for (int tIdx = t0; tIdx < t1; ++tIdx) {
        __syncthreads();
        *(usx8*)&Ks[prow][scol]     = kr0;
        *(usx8*)&Ks[prow][scol + 8] = kr1;
        #pragma unroll
        for (int i = 0; i < 8; ++i)
          *(unsigned*)&Vt[vchunk*8 + i][2*kpair] =
              (unsigned)vr0[i] | ((unsigned)vr1[i] << 16);
        __syncthreads();

        if (tIdx + 1 < t1) {
          const int kn = (tIdx + 1) << 6;
          const u16* kp = qkv + base + (size_t)(kn + kmap) * 3072 + koff + scol;
          kr0 = *(const usx8*)kp; kr1 = *(const usx8*)(kp + 8);
          const u16* vp = qkv + base + (size_t)(kn + 2*kpair) * 3072 + voff + vchunk*8;
          vr0 = *(const usx8*)vp; vr1 = *(const usx8*)(vp + 3072);
        }

        const int k0 = tIdx << 6;
        floatx4 sf[4];
        #pragma unroll
        for (int kt = 0; kt < 4; ++kt) {
          short8 kf0 = *(const short8*)&Ks[kt*16 + l16][quad*8];
          short8 kf1 = *(const short8*)&Ks[kt*16 + l16][32 + quad*8];
          floatx4 z = {};
          z      = __builtin_amdgcn_mfma_f32_16x16x32_bf16(qf0, kf0, z, 0, 0, 0);
          sf[kt] = __builtin_amdgcn_mfma_f32_16x16x32_bf16(qf1, kf1, z, 0, 0, 0);
        }

        const bool diag = (tIdx == qi);
        #pragma unroll
        for (int r = 0; r < 4; ++r) {
          float sv0 = sf[0][r], sv1 = sf[1][r], sv2 = sf[2][r], sv3 = sf[3][r];
          if (diag) {
            const int qrow = q0 + wave*16 + quad*4 + r;
            const int kbase = k0 + 4*l16;
            if (kbase     > qrow) sv0 = -1e30f;
            if (kbase + 1 > qrow) sv1 = -1e30f;
            if (kbase + 2 > qrow) sv2 = -1e30f;
            if (kbase + 3 > qrow) sv3 = -1e30f;
          }
          float mx = fmaxf(fmaxf(sv0, sv1), fmaxf(sv2, sv3));
          mx = rowmax16(mx);
          const float nm = fmaxf(m[r], mx);
          const float alpha = __builtin_amdgcn_exp2f(m[r] - nm);
          m[r] = nm;
          const float p0 = __builtin_amdgcn_exp2f(sv0 - nm);
          const float p1 = __builtin_amdgcn_exp2f(sv1 - nm);
          const float p2 = __builtin_amdgcn_exp2f(sv2 - nm);
          const float p3 = __builtin_amdgcn_exp2f(sv3 - nm);
          uintx2 pw = { cvt_pk_bf16(p0, p1), cvt_pk_bf16(p2, p3) };
          *(uintx2*)&Ps[wave*16 + quad*4 + r][l16 * 4] = pw;
          #pragma unroll
          for (int dht = 0; dht < 4; ++dht) of[dht][r] *= alpha;
          ofl[r] *= alpha;
        }

        short8 pf0 = *(const short8*)&Ps[wave*16 + l16][quad*8];
        short8 pf1 = *(const short8*)&Ps[wave*16 + l16][32 + quad*8];
        #pragma unroll
        for (int dht = 0; dht < 4; ++dht) {
          short8 vf0 = *(const short8*)&Vt[dht*16 + l16][quad*8];
          short8 vf1 = *(const short8*)&Vt[dht*16 + l16][32 + quad*8];
          of[dht] = __builtin_amdgcn_mfma_f32_16x16x32_bf16(pf0, vf0, of[dht], 0, 0, 0);
          of[dht] = __builtin_amdgcn_mfma_f32_16x16x32_bf16(pf1, vf1, of[dht], 0, 0, 0);
        }
        ofl = __builtin_amdgcn_mfma_f32_16x16x32_bf16(pf0, onesb, ofl, 0, 0, 0);
        ofl = __builtin_amdgcn_mfma_f32_16x16x32_bf16(pf1, onesb, ofl, 0, 0, 0);
      }
    }

    #pragma unroll
    for (int r = 0; r < 4; ++r) {
      const int s = q0 + wave*16 + quad*4 + r;
      u16* orow = opart + obase + (size_t)s * 64;
      #pragma unroll
      for (int dht = 0; dht < 4; ++dht) orow[dht*16 + l16] = f2b(of[dht][r]);
      const float lr = __shfl(ofl[r], quad * 16);
      if (l16 == 0) { ml[mlbase + 2*s] = m[r]; ml[mlbase + 2*s + 1] = lr; }
    }
  }
}

// ---------- combine attention partials -> attnb bf16 [B,S,1024] ----------
__global__ __launch_bounds__(256) void attn_combine_kernel(
    const u16* __restrict__ opart, const float* __restrict__ ml,
    u16* __restrict__ out)
{
  const int t = threadIdx.x;
  const int s = blockIdx.x * 4 + (t >> 6);
  const int lane = t & 63;
  const int h = blockIdx.y, b = blockIdx.z;

  const size_t o0  = ((((size_t)0 * 2 + b) * 16 + h) * 2048 + s) * 64 + lane;
  const size_t o1  = ((((size_t)1 * 2 + b) * 16 + h) * 2048 + s) * 64 + lane;
  const size_t ml0 = ((((size_t)0 * 2 + b) * 16 + h) * 2048 + s) * 2;
  const size_t ml1 = ((((size_t)1 * 2 + b) * 16 + h) * 2048 + s) * 2;

  const float m0 = ml[ml0], l0 = ml[ml0 + 1];
  const float m1 = ml[ml1], l1 = ml[ml1 + 1];
  const float M  = fmaxf(m0, m1);
  const float w0 = __builtin_amdgcn_exp2f(m0 - M);
  const float w1 = __builtin_amdgcn_exp2f(m1 - M);
  const float L  = w0 * l0 + w1 * l1;
  const float o  = w0 * b2f(opart[o0]) + w1 * b2f(opart[o1]);
  out[((size_t)b * 2048 + s) * 1024 + h * 64 + lane] = f2b(o / L);
}

// ---------- K-split combine: out(fp32) = res + sum(p[z]) + bias ----------
template<int NP>
__global__ __launch_bounds__(256) void ksplit_combine_kernel(
    const u16* __restrict__ pp, size_t pstride,
    const float* __restrict__ res, const float* __restrict__ bias,
    float* __restrict__ out)
{
  const size_t i0 = ((size_t)blockIdx.x * 256 + threadIdx.x) * 8;
  usx8 a[NP];
  #pragma unroll
  for (int z = 0; z < NP; ++z) a[z] = *(const usx8*)(pp + z * pstride + i0);
  const int col = (int)(i0 & 1023);
  floatx4 bv0 = *(const floatx4*)(bias + col);
  floatx4 bv1 = *(const floatx4*)(bias + col + 4);
  floatx4 h0 = *(const floatx4*)(res + i0);
  floatx4 h1 = *(const floatx4*)(res + i0 + 4);
  floatx4 o0, o1;
  #pragma unroll
  for (int i = 0; i < 4; ++i) {
    float s0 = h0[i] + bv0[i], s1 = h1[i] + bv1[i];
    #pragma unroll
    for (int z = 0; z < NP; ++z) { s0 += b2f(a[z][i]); s1 += b2f(a[z][4+i]); }
    o0[i] = s0; o1[i] = s1;
  }
  *(floatx4*)(out + i0)     = o0;
  *(floatx4*)(out + i0 + 4) = o1;
}

// ---------- launch ----------
extern "C" void kernel_launch(void* const* d_in, const int* in_sizes, int n_in,
                              void* d_out, int out_size, void* d_ws, size_t ws_size,
                              hipStream_t stream) {
  const float* hidden    = (const float*)d_in[0];
  const float* w_attn    = (const float*)d_in[1];
  const float* b_attn    = (const float*)d_in[2];
  const float* w_proj    = (const float*)d_in[3];
  const float* b_proj    = (const float*)d_in[4];
  const float* w_fc      = (const float*)d_in[5];
  const float* b_fc      = (const float*)d_in[6];
  const float* w_fc_proj = (const float*)d_in[7];
  const float* b_fc_proj = (const float*)d_in[8];
  const float* ln1_w     = (const float*)d_in[9];
  const float* ln1_b     = (const float*)d_in[10];
  const float* ln2_w     = (const float*)d_in[11];
  const float* ln2_b     = (const float*)d_in[12];

  // Workspace layout (MB offsets) — round-8 verified layout
  char* wsb = (char*)d_ws;
  u16*   qkvb  = (u16*)  (wsb + (size_t)( 0u << 20));  // 24 MB [4096,3072]
  u16*   xb    = (u16*)  (wsb + (size_t)(24u << 20));  //  8 MB [4096,1024]
  u16*   opart = (u16*)  (wsb + (size_t)(24u << 20));  // 16 MB (xb dead)
  float* mlbuf = (float*)(wsb + (size_t)(40u << 20));  //  2 MB
  u16*   attnb = (u16*)  (wsb + (size_t)(42u << 20));  //  8 MB [4096,1024]
  u16*   wqT   = (u16*)  (wsb + (size_t)(50u << 20));  //  6 MB [3072,1024]
  u16*   wpT   = (u16*)  (wsb + (size_t)(56u << 20));  //  2 MB [1024,1024]
  u16*   wfT   = (u16*)  (wsb + (size_t)(58u << 20));  //  8 MB [4096,1024]
  u16*   wfpT  = (u16*)  (wsb + (size_t)(66u << 20));  //  8 MB [1024,4096]
  u16*   pproj = (u16*)  (wsb + (size_t)(24u << 20));  // 16 MB (opart dead)
  float* hbuf  = (float*)(wsb + (size_t)(42u << 20));  // 16 MB fp32
  u16*   yb    = (u16*)  (wsb + (size_t)( 0u << 20));  //  8 MB (qkvb dead)
  u16*   fcb   = (u16*)  (wsb + (size_t)( 8u << 20));  // 32 MB
  u16*   p4    = (u16*)  (wsb + (size_t)(74u << 20));  // BIG: 4x8MB partials
  u16*   pfcp0 = (u16*)  (wsb + (size_t)( 0u << 20));  // fallback z0
  const size_t zstr8  = ((size_t)8u << 20) / 2;        // 8 MB in u16 elems
  const size_t zstr58 = ((size_t)58u << 20) / 2;       // fallback stride

  const bool big = ws_size >= ((size_t)106u << 20);

  // 0) weight transpose+convert
  wtrans4_kernel<<<dim3(12288), 256, 0, stream>>>(
      w_attn, w_proj, w_fc, w_fc_proj, wqT, wpT, wfT, wfpT);

  // 1) x = LN1(hidden) -> bf16
  ln_bf16_kernel<<<4096, 256, 0, stream>>>(hidden, ln1_w, ln1_b, xb);
  // 2) qkv = x @ w_attn + b_attn -> bf16; q pre-scaled (flag 8); 768 blocks
  gemm_mfma_kernel<128,128,12,4, 24,32,1, 2,4,1><<<dim3(24, 32, 1), 256, 0, stream>>>(
      xb, wqT, b_attn, nullptr, qkvb, 4096, 3072, 1024, 1024, 0);
  // 3) flash attention partials (XCD-clustered) + combine
  attn_mfma_kernel<<<dim3(32, 16, 2), 256, 0, stream>>>(qkvb, opart, mlbuf);
  attn_combine_kernel<<<dim3(512, 16, 2), 256, 0, stream>>>(opart, mlbuf, attnb);

  // 4) proj partials: K-split x2, 128x64 tile (round-3 config — best measured)
  gemm_mfma_kernel<128,64,4,4, 16,32,2, 1,4,2><<<dim3(16, 32, 2), 256, 0, stream>>>(
      attnb, wpT, nullptr, nullptr, pproj, 4096, 1024, 1024, 512, zstr8);
  // 4b+5) h = hidden + p0 + p1 + b_proj; y = LN2(h)
  combine_ln_kernel<2><<<4096, 256, 0, stream>>>(
      pproj, zstr8, hidden, b_proj, ln2_w, ln2_b, hbuf, yb);
  // 6) fc = gelu(y @ w_fc + b_fc); 1024 blocks (round-3 config)
  gemm_mfma_kernel<128,128,5,4, 32,32,1, 2,4,1><<<dim3(32, 32, 1), 256, 0, stream>>>(
      yb, wfT, b_fc, nullptr, fcb, 4096, 4096, 1024, 1024, 0);
  if (big) {
    // 7) fc_proj partials: K-split x4, 128x128 tile (round-5 measured −9 µs)
    gemm_mfma_kernel<128,128,4,4, 8,32,4, 1,2,4><<<dim3(8, 32, 4), 256, 0, stream>>>(
        fcb, wfpT, nullptr, nullptr, p4, 4096, 1024, 4096, 1024, zstr8);
    // 8) out = h + sum(p) + b_fc_proj -> fp32
    ksplit_combine_kernel<4><<<dim3(2048), 256, 0, stream>>>(
        p4, zstr8, hbuf, b_fc_proj, (float*)d_out);
  } else {
    gemm_mfma_kernel<128,64,4,4, 16,32,2, 1,4,2><<<dim3(16, 32, 2), 256, 0, stream>>>(
        fcb, wfpT, nullptr, nullptr, pfcp0, 4096, 1024, 4096, 2048, zstr58);
    ksplit_combine_kernel<2><<<dim3(2048), 256, 0, stream>>>(
        pfcp0, zstr58, hbuf, b_fc_proj, (float*)d_out);
  }
}

// Round 11
// 335.452 us; speedup vs baseline: 1.2759x; 1.0308x over previous
//
#include <hip/hip_runtime.h>
#include <cstdint>
#include <cstddef>

// ---------- types ----------
typedef unsigned short u16;
typedef float  floatx4 __attribute__((ext_vector_type(4)));
typedef short  short8  __attribute__((ext_vector_type(8)));
typedef u16    usx4    __attribute__((ext_vector_type(4)));
typedef u16    usx8    __attribute__((ext_vector_type(8)));
typedef unsigned uintx2 __attribute__((ext_vector_type(2)));

// fp32 -> bf16, round-to-nearest-even
__device__ __forceinline__ u16 f2b(float f) {
  unsigned u = __float_as_uint(f);
  unsigned r = u + 0x7fffu + ((u >> 16) & 1u);
  return (u16)(r >> 16);
}
__device__ __forceinline__ float b2f(u16 s) {
  return __uint_as_float(((unsigned)s) << 16);
}

// packed fp32x2 -> bf16x2 (hardware RNE); no builtin on gfx950 -> inline asm
__device__ __forceinline__ unsigned cvt_pk_bf16(float lo, float hi) {
  unsigned r;
  asm("v_cvt_pk_bf16_f32 %0, %1, %2" : "=v"(r) : "v"(lo), "v"(hi));
  return r;
}

// max across each 16-lane row via DPP (VALU-only)
__device__ __forceinline__ float rowmax16(float x) {
  int xi = __float_as_int(x), y;
  y = __builtin_amdgcn_update_dpp(xi, xi, 0xB1, 0xF, 0xF, false);  // quad_perm xor1
  x = fmaxf(x, __int_as_float(y)); xi = __float_as_int(x);
  y = __builtin_amdgcn_update_dpp(xi, xi, 0x4E, 0xF, 0xF, false);  // quad_perm xor2
  x = fmaxf(x, __int_as_float(y)); xi = __float_as_int(x);
  y = __builtin_amdgcn_update_dpp(xi, xi, 0x141, 0xF, 0xF, false); // row_half_mirror
  x = fmaxf(x, __int_as_float(y)); xi = __float_as_int(x);
  y = __builtin_amdgcn_update_dpp(xi, xi, 0x140, 0xF, 0xF, false); // row_mirror
  x = fmaxf(x, __int_as_float(y));
  return x;
}

// GPT-2 tanh-gelu, exact algebraic rewrite: 0.5x(1+tanh(u)) = x*sigmoid(2u)
__device__ __forceinline__ float gelu_f(float x) {
  const float k = 2.3022082f;  // 2*sqrt(2/pi)*log2(e)
  float u = x * (1.0f + 0.044715f * x * x);
  float t = __builtin_amdgcn_exp2f(-k * u);
  return x * __builtin_amdgcn_rcpf(1.0f + t);
}

// async global->LDS 16B: lds dst = wave-uniform base + lane*16 (HW rule)
__device__ __forceinline__ void gl2lds16(const u16* g, u16* l) {
  __builtin_amdgcn_global_load_lds(
      (const __attribute__((address_space(1))) unsigned int*)g,
      (__attribute__((address_space(3))) unsigned int*)l, 16, 0, 0);
}

// counted vmcnt wait + raw barrier (T4: younger loads stay in flight)
template<int N> __device__ __forceinline__ void wait_stage_barrier() {
  asm volatile("s_waitcnt vmcnt(%0)" :: "n"(N) : "memory");
  __builtin_amdgcn_s_barrier();
  __builtin_amdgcn_sched_barrier(0);
}
// raw barrier after compute, before re-staging the freed buffer
__device__ __forceinline__ void post_barrier() {
  __builtin_amdgcn_sched_barrier(0);
  __builtin_amdgcn_s_barrier();
  __builtin_amdgcn_sched_barrier(0);
}

#define C2SCALE 0.18033688011112042f  // (1/8) * log2(e)

// ---------- LayerNorm: one block per row of 1024, bf16 out ----------
__global__ __launch_bounds__(256) void ln_bf16_kernel(
    const float* __restrict__ in, const float* __restrict__ w,
    const float* __restrict__ b, u16* __restrict__ out)
{
  const int row = blockIdx.x;
  const int t = threadIdx.x;
  const float* p = in + (size_t)row * 1024 + t * 4;
  floatx4 v = *(const floatx4*)p;
  float s  = v.x + v.y + v.z + v.w;
  float ss = v.x*v.x + v.y*v.y + v.z*v.z + v.w*v.w;
  #pragma unroll
  for (int m = 1; m < 64; m <<= 1) {
    s  += __shfl_xor(s,  m);
    ss += __shfl_xor(ss, m);
  }
  __shared__ float red[8];
  if ((t & 63) == 0) { red[(t >> 6)*2] = s; red[(t >> 6)*2 + 1] = ss; }
  __syncthreads();
  s  = red[0] + red[2] + red[4] + red[6];
  ss = red[1] + red[3] + red[5] + red[7];
  const float mean = s * (1.0f / 1024.0f);
  const float var  = ss * (1.0f / 1024.0f) - mean * mean;
  const float rstd = rsqrtf(var + 1e-6f);
  floatx4 wv = *(const floatx4*)(w + t * 4);
  floatx4 bv = *(const floatx4*)(b + t * 4);
  usx4 o = { f2b(wv.x * ((v.x - mean) * rstd) + bv.x),
             f2b(wv.y * ((v.y - mean) * rstd) + bv.y),
             f2b(wv.z * ((v.z - mean) * rstd) + bv.z),
             f2b(wv.w * ((v.w - mean) * rstd) + bv.w) };
  *(usx4*)(out + (size_t)row * 1024 + t * 4) = o;
}

// ---------- fused K-split combine + LayerNorm (NP partials) ----------
template<int NP>
__global__ __launch_bounds__(256) void combine_ln_kernel(
    const u16* __restrict__ pp, size_t pstride,
    const float* __restrict__ res, const float* __restrict__ bias,
    const float* __restrict__ w, const float* __restrict__ b,
    float* __restrict__ hout, u16* __restrict__ yout)
{
  const int row = blockIdx.x;
  const int t = threadIdx.x;
  const size_t i0 = (size_t)row * 1024 + t * 4;
  floatx4 rv = *(const floatx4*)(res + i0);
  usx4 a[NP];
  #pragma unroll
  for (int z = 0; z < NP; ++z) a[z] = *(const usx4*)(pp + z * pstride + i0);
  floatx4 biasv = *(const floatx4*)(bias + t * 4);
  floatx4 v;
  #pragma unroll
  for (int i = 0; i < 4; ++i) {
    float acc = rv[i] + biasv[i];
    #pragma unroll
    for (int z = 0; z < NP; ++z) acc += b2f(a[z][i]);
    v[i] = acc;
  }
  *(floatx4*)(hout + i0) = v;

  float s  = v.x + v.y + v.z + v.w;
  float ss = v.x*v.x + v.y*v.y + v.z*v.z + v.w*v.w;
  #pragma unroll
  for (int m = 1; m < 64; m <<= 1) {
    s  += __shfl_xor(s,  m);
    ss += __shfl_xor(ss, m);
  }
  __shared__ float red[8];
  if ((t & 63) == 0) { red[(t >> 6)*2] = s; red[(t >> 6)*2 + 1] = ss; }
  __syncthreads();
  s  = red[0] + red[2] + red[4] + red[6];
  ss = red[1] + red[3] + red[5] + red[7];
  const float mean = s * (1.0f / 1024.0f);
  const float var  = ss * (1.0f / 1024.0f) - mean * mean;
  const float rstd = rsqrtf(var + 1e-6f);
  floatx4 wv = *(const floatx4*)(w + t * 4);
  floatx4 bv = *(const floatx4*)(b + t * 4);
  usx4 o = { f2b(wv.x * ((v.x - mean) * rstd) + bv.x),
             f2b(wv.y * ((v.y - mean) * rstd) + bv.y),
             f2b(wv.z * ((v.z - mean) * rstd) + bv.z),
             f2b(wv.w * ((v.w - mean) * rstd) + bv.w) };
  *(usx4*)(yout + i0) = o;
}

// ---------- weight transpose+convert: 4 weights in one launch ----------
__device__ __forceinline__ void wtrans_body(
    const float* __restrict__ in, u16* __restrict__ out, int K, int N,
    int bx, int by, int tx, int ty)
{
  __shared__ u16 tile[32][33];
  const int n0 = bx * 32, k0 = by * 32;
  #pragma unroll
  for (int i = 0; i < 4; ++i)
    tile[ty + i*8][tx] = f2b(in[(size_t)(k0 + ty + i*8) * N + n0 + tx]);
  __syncthreads();
  #pragma unroll
  for (int i = 0; i < 4; ++i)
    out[(size_t)(n0 + ty + i*8) * K + k0 + tx] = tile[tx][ty + i*8];
}

__global__ __launch_bounds__(256) void wtrans4_kernel(
    const float* __restrict__ w0, const float* __restrict__ w1,
    const float* __restrict__ w2, const float* __restrict__ w3,
    u16* __restrict__ o0, u16* __restrict__ o1,
    u16* __restrict__ o2, u16* __restrict__ o3)
{
  int blk = blockIdx.x;
  const int tx = threadIdx.x & 31, ty = threadIdx.x >> 5;
  if (blk < 3072) {
    wtrans_body(w0, o0, 1024, 3072, blk % 96, blk / 96, tx, ty);
  } else if (blk < 4096) {
    blk -= 3072; wtrans_body(w1, o1, 1024, 1024, blk % 32, blk / 32, tx, ty);
  } else if (blk < 8192) {
    blk -= 4096; wtrans_body(w2, o2, 1024, 4096, blk % 128, blk / 128, tx, ty);
  } else {
    blk -= 8192; wtrans_body(w3, o3, 4096, 1024, blk % 32, blk / 32, tx, ty);
  }
}

// ---------- GEMM: C[M,N] = A[M,K] @ Bt[N,K]^T ----------
// m97 tile + T4 counted-vmcnt pipeline at 2 LDS buffers (round-3 verified):
//   phase ti: s_waitcnt vmcnt(L) -> s_barrier -> compute(buf) -> s_barrier
//             -> stage(ti+2 into buf)
// FLAGS: 1 = gelu, 2 = +Res (fp32), 4 = bf16 out, 8 = scale cols<1024 by C2
template<int BM, int BN, int FLAGS, int MINW,
         int NX, int NY, int NZ, int RX, int RY, int RZ>
__global__ __launch_bounds__(256, MINW) void gemm_mfma_kernel(
    const u16* __restrict__ A, const u16* __restrict__ Bt,
    const float* __restrict__ bias, const float* __restrict__ Res,
    void* __restrict__ Cout, int M, int N, int K, int kLen, size_t zStride)
{
  constexpr int WM = BM / 2, WN = BN / 2;
  constexpr int MT = WM / 16, NT = WN / 16;
  constexpr int GX = NX / RX, GY = NY / RY, GZ = NZ / RZ;
  constexpr int ABUF = BM * 32, BBUF = BN * 32;
  constexpr int L = BM / 64 + BN / 64;
  __shared__ u16 As[2 * ABUF];
  __shared__ u16 Bs[2 * BBUF];

  const int lin = blockIdx.x + NX * (blockIdx.y + NY * blockIdx.z);
  const int xcd = lin & 7;
  const int idx = lin >> 3;
  const int rx = xcd % RX, ry = (xcd / RX) % RY, rz = xcd / (RX * RY);
  const int bx = rx * GX + idx % GX;
  const int by = ry * GY + (idx / GX) % GY;
  const int bz = rz * GZ + idx / (GX * GY);

  const int t = threadIdx.x;
  const int wave = t >> 6, lane = t & 63;
  const int quad = lane >> 4, l16 = lane & 15;
  const int wm = wave >> 1, wn = wave & 1;
  const int bm0 = by * BM, bn0 = bx * BN;
  const int kStart = bz * kLen;

  const int sRow = lane >> 2;
  const int sq   = (lane & 3) ^ ((lane >> 4) & 3);

  const u16* aG[BM / 64];
  u16* aL[BM / 64];
  #pragma unroll
  for (int j = 0; j < BM / 64; ++j) {
    const int band = j * 4 + wave;
    aG[j] = A + (size_t)(bm0 + band * 16 + sRow) * K + kStart + sq * 8;
    aL[j] = As + band * 512;
  }
  const u16* bG[BN / 64];
  u16* bL[BN / 64];
  #pragma unroll
  for (int j = 0; j < BN / 64; ++j) {
    const int band = j * 4 + wave;
    bG[j] = Bt + (size_t)(bn0 + band * 16 + sRow) * K + kStart + sq * 8;
    bL[j] = Bs + band * 512;
  }

  floatx4 acc[MT][NT] = {};
  const int rcol = (quad ^ (l16 >> 2)) << 3;

  auto stage = [&](int tile, int buf) {
    #pragma unroll
    for (int j = 0; j < BM / 64; ++j) gl2lds16(aG[j] + tile * 32, aL[j] + buf * ABUF);
    #pragma unroll
    for (int j = 0; j < BN / 64; ++j) gl2lds16(bG[j] + tile * 32, bL[j] + buf * BBUF);
  };
  auto compute = [&](int buf) {
    const u16* Asc = As + buf * ABUF;
    const u16* Bsc = Bs + buf * BBUF;
    short8 af[MT], bf[NT];
    #pragma unroll
    for (int mt = 0; mt < MT; ++mt)
      af[mt] = *(const short8*)&Asc[(wm*WM + mt*16 + l16) * 32 + rcol];
    #pragma unroll
    for (int nt = 0; nt < NT; ++nt)
      bf[nt] = *(const short8*)&Bsc[(wn*WN + nt*16 + l16) * 32 + rcol];
    __builtin_amdgcn_s_setprio(1);
    #pragma unroll
    for (int mt = 0; mt < MT; ++mt)
      #pragma unroll
      for (int nt = 0; nt < NT; ++nt)
        acc[mt][nt] = __builtin_amdgcn_mfma_f32_16x16x32_bf16(af[mt], bf[nt], acc[mt][nt], 0, 0, 0);
    __builtin_amdgcn_s_setprio(0);
  };

  const int nt = kLen >> 5;
  stage(0, 0);
  stage(1, 1);
  #pragma unroll 1
  for (int ti = 0; ti < nt - 2; ti += 2) {
    wait_stage_barrier<L>();
    compute(0);
    post_barrier();
    stage(ti + 2, 0);
    wait_stage_barrier<L>();
    compute(1);
    post_barrier();
    stage(ti + 3, 1);
  }
  wait_stage_barrier<L>();
  compute(0);
  wait_stage_barrier<0>();
  compute(1);

  const int orow0 = bm0 + wm * WM;
  const int ocol0 = bn0 + wn * WN;
  const size_t zoff = (size_t)bz * zStride;
  #pragma unroll
  for (int nt2 = 0; nt2 < NT; ++nt2) {
    const int col = ocol0 + nt2*16 + l16;
    const float bv = bias ? bias[col] : 0.0f;
    const float postscale = ((FLAGS & 8) && col < 1024) ? C2SCALE : 1.0f;
    #pragma unroll
    for (int mt = 0; mt < MT; ++mt) {
      #pragma unroll
      for (int r = 0; r < 4; ++r) {
        const int row = orow0 + mt*16 + quad*4 + r;
        float v = acc[mt][nt2][r] + bv;
        if (FLAGS & 1) v = gelu_f(v);
        if (FLAGS & 8) v *= postscale;
        if (FLAGS & 2) v += Res[(size_t)row * N + col];
        if (FLAGS & 4) ((u16*)Cout)[zoff + (size_t)row * N + col] = f2b(v);
        else           ((float*)Cout)[zoff + (size_t)row * N + col] = v;
      }
    }
  }
}

// ---------- MFMA flash attention (causal), bf16, balanced + K-split ----------
// Round-3/5/8 verified compute; XCD-clustered block remap (round-9 verified):
// all 32 blocks sharing one (h,b)'s K/V stream land on ONE XCD.
__global__ __launch_bounds__(256, 4) void attn_mfma_kernel(
    const u16* __restrict__ qkv, u16* __restrict__ opart, float* __restrict__ ml)
{
  __shared__ u16 Ks[64][72];
  __shared__ u16 Vt[64][72];
  __shared__ u16 Ps[64][72];

  const int t    = threadIdx.x;
  const int wave = t >> 6;
  const int lane = t & 63;
  const int quad = lane >> 4;
  const int l16  = lane & 15;

  // ---- XCD-clustered remap: lin -> (xcd, idx) -> (hb, xr) ----
  const int lin  = blockIdx.x + 32 * (blockIdx.y + 16 * blockIdx.z);
  const int xcd  = lin & 7;
  const int idx  = lin >> 3;            // 0..127
  const int hb   = xcd * 4 + (idx >> 5);// 0..31 (4 (h,b) combos per XCD)
  const int xr   = idx & 31;            // 0..31 within (h,b)
  const int pair = xr >> 1;
  const int half = xr & 1;
  const int h    = hb & 15;
  const int b    = hb >> 4;

  const size_t base = (size_t)b * 2048 * 3072;
  const int qoff = h * 64;
  const int koff = 1024 + h * 64;
  const int voff = 2048 + h * 64;

  const int prow = t >> 2;
  const int scol = (t & 3) * 16;
  const int kmap = ((prow & 15) << 2) | (prow >> 4);
  const int kpair  = t & 31;
  const int vchunk = t >> 5;

  const size_t obase  = ((((size_t)half * 2 + b) * 16 + h) * 2048) * 64;
  const size_t mlbase = ((((size_t)half * 2 + b) * 16 + h) * 2048) * 2;

  short8 onesb;
  {
    const short v = (l16 == 0) ? (short)0x3F80 : (short)0;
    #pragma unroll
    for (int i = 0; i < 8; ++i) onesb[i] = v;
  }

  #pragma unroll 1
  for (int iter = 0; iter < 2; ++iter) {
    const int qi = iter ? (31 - pair) : pair;
    const int q0 = qi << 6;
    const int T  = qi + 1;
    const int mid = (T + 1) >> 1;
    const int t0 = half ? mid : 0;
    const int t1 = half ? T : mid;

    floatx4 of[4] = {};
    floatx4 ofl = {};
    float m[4];
    #pragma unroll
    for (int r = 0; r < 4; ++r) m[r] = -1e30f;

    if (t0 < t1) {
      __syncthreads();
      {
        const u16* qp = qkv + base + (size_t)(q0 + prow) * 3072 + qoff + scol;
        *(usx8*)&Ks[prow][scol]     = *(const usx8*)qp;
        *(usx8*)&Ks[prow][scol + 8] = *(const usx8*)(qp + 8);
      }
      __syncthreads();
      const short8 qf0 = *(const short8*)&Ks[wave*16 + l16][quad*8];
      const short8 qf1 = *(const short8*)&Ks[wave*16 + l16][32 + quad*8];

      usx8 kr0, kr1, vr0, vr1;
      {
        const int k0 = t0 << 6;
        const u16* kp = qkv + base + (size_t)(k0 + kmap) * 3072 + koff + scol;
        kr0 = *(const usx8*)kp; kr1 = *(const usx8*)(kp + 8);
        const u16* vp = qkv + base + (size_t)(k0 + 2*kpair) * 3072 + voff + vchunk*8;
        vr0 = *(const usx8*)vp; vr1 = *(const usx8*)(vp + 3072);
      }

      for (int tIdx = t0; tIdx < t1; ++tIdx) {
        __syncthreads();
        *(usx8*)&Ks[prow][scol]     = kr0;
        *(usx8*)&Ks[prow][scol + 8] = kr1;
        #pragma unroll
        for (int i = 0; i < 8; ++i)
          *(unsigned*)&Vt[vchunk*8 + i][2*kpair] =
              (unsigned)vr0[i] | ((unsigned)vr1[i] << 16);
        __syncthreads();

        if (tIdx + 1 < t1) {
          const int kn = (tIdx + 1) << 6;
          const u16* kp = qkv + base + (size_t)(kn + kmap) * 3072 + koff + scol;
          kr0 = *(const usx8*)kp; kr1 = *(const usx8*)(kp + 8);
          const u16* vp = qkv + base + (size_t)(kn + 2*kpair) * 3072 + voff + vchunk*8;
          vr0 = *(const usx8*)vp; vr1 = *(const usx8*)(vp + 3072);
        }

        const int k0 = tIdx << 6;
        floatx4 sf[4];
        #pragma unroll
        for (int kt = 0; kt < 4; ++kt) {
          short8 kf0 = *(const short8*)&Ks[kt*16 + l16][quad*8];
          short8 kf1 = *(const short8*)&Ks[kt*16 + l16][32 + quad*8];
          floatx4 z = {};
          z      = __builtin_amdgcn_mfma_f32_16x16x32_bf16(qf0, kf0, z, 0, 0, 0);
          sf[kt] = __builtin_amdgcn_mfma_f32_16x16x32_bf16(qf1, kf1, z, 0, 0, 0);
        }

        const bool diag = (tIdx == qi);
        #pragma unroll
        for (int r = 0; r < 4; ++r) {
          float sv0 = sf[0][r], sv1 = sf[1][r], sv2 = sf[2][r], sv3 = sf[3][r];
          if (diag) {
            const int qrow = q0 + wave*16 + quad*4 + r;
            const int kbase = k0 + 4*l16;
            if (kbase     > qrow) sv0 = -1e30f;
            if (kbase + 1 > qrow) sv1 = -1e30f;
            if (kbase + 2 > qrow) sv2 = -1e30f;
            if (kbase + 3 > qrow) sv3 = -1e30f;
          }
          float mx = fmaxf(fmaxf(sv0, sv1), fmaxf(sv2, sv3));
          mx = rowmax16(mx);
          const float nm = fmaxf(m[r], mx);
          const float alpha = __builtin_amdgcn_exp2f(m[r] - nm);
          m[r] = nm;
          const float p0 = __builtin_amdgcn_exp2f(sv0 - nm);
          const float p1 = __builtin_amdgcn_exp2f(sv1 - nm);
          const float p2 = __builtin_amdgcn_exp2f(sv2 - nm);
          const float p3 = __builtin_amdgcn_exp2f(sv3 - nm);
          uintx2 pw = { cvt_pk_bf16(p0, p1), cvt_pk_bf16(p2, p3) };
          *(uintx2*)&Ps[wave*16 + quad*4 + r][l16 * 4] = pw;
          #pragma unroll
          for (int dht = 0; dht < 4; ++dht) of[dht][r] *= alpha;
          ofl[r] *= alpha;
        }

        short8 pf0 = *(const short8*)&Ps[wave*16 + l16][quad*8];
        short8 pf1 = *(const short8*)&Ps[wave*16 + l16][32 + quad*8];
        #pragma unroll
        for (int dht = 0; dht < 4; ++dht) {
          short8 vf0 = *(const short8*)&Vt[dht*16 + l16][quad*8];
          short8 vf1 = *(const short8*)&Vt[dht*16 + l16][32 + quad*8];
          of[dht] = __builtin_amdgcn_mfma_f32_16x16x32_bf16(pf0, vf0, of[dht], 0, 0, 0);
          of[dht] = __builtin_amdgcn_mfma_f32_16x16x32_bf16(pf1, vf1, of[dht], 0, 0, 0);
        }
        ofl = __builtin_amdgcn_mfma_f32_16x16x32_bf16(pf0, onesb, ofl, 0, 0, 0);
        ofl = __builtin_amdgcn_mfma_f32_16x16x32_bf16(pf1, onesb, ofl, 0, 0, 0);
      }
    }

    #pragma unroll
    for (int r = 0; r < 4; ++r) {
      const int s = q0 + wave*16 + quad*4 + r;
      u16* orow = opart + obase + (size_t)s * 64;
      #pragma unroll
      for (int dht = 0; dht < 4; ++dht) orow[dht*16 + l16] = f2b(of[dht][r]);
      const float lr = __shfl(ofl[r], quad * 16);
      if (l16 == 0) { ml[mlbase + 2*s] = m[r]; ml[mlbase + 2*s + 1] = lr; }
    }
  }
}

// ---------- combine attention partials -> attnb bf16 [B,S,1024] ----------
__global__ __launch_bounds__(256) void attn_combine_kernel(
    const u16* __restrict__ opart, const float* __restrict__ ml,
    u16* __restrict__ out)
{
  const int t = threadIdx.x;
  const int s = blockIdx.x * 4 + (t >> 6);
  const int lane = t & 63;
  const int h = blockIdx.y, b = blockIdx.z;

  const size_t o0  = ((((size_t)0 * 2 + b) * 16 + h) * 2048 + s) * 64 + lane;
  const size_t o1  = ((((size_t)1 * 2 + b) * 16 + h) * 2048 + s) * 64 + lane;
  const size_t ml0 = ((((size_t)0 * 2 + b) * 16 + h) * 2048 + s) * 2;
  const size_t ml1 = ((((size_t)1 * 2 + b) * 16 + h) * 2048 + s) * 2;

  const float m0 = ml[ml0], l0 = ml[ml0 + 1];
  const float m1 = ml[ml1], l1 = ml[ml1 + 1];
  const float M  = fmaxf(m0, m1);
  const float w0 = __builtin_amdgcn_exp2f(m0 - M);
  const float w1 = __builtin_amdgcn_exp2f(m1 - M);
  const float L  = w0 * l0 + w1 * l1;
  const float o  = w0 * b2f(opart[o0]) + w1 * b2f(opart[o1]);
  out[((size_t)b * 2048 + s) * 1024 + h * 64 + lane] = f2b(o / L);
}

// ---------- K-split combine: out(fp32) = res + sum(p[z]) + bias ----------
template<int NP>
__global__ __launch_bounds__(256) void ksplit_combine_kernel(
    const u16* __restrict__ pp, size_t pstride,
    const float* __restrict__ res, const float* __restrict__ bias,
    float* __restrict__ out)
{
  const size_t i0 = ((size_t)blockIdx.x * 256 + threadIdx.x) * 8;
  usx8 a[NP];
  #pragma unroll
  for (int z = 0; z < NP; ++z) a[z] = *(const usx8*)(pp + z * pstride + i0);
  const int col = (int)(i0 & 1023);
  floatx4 bv0 = *(const floatx4*)(bias + col);
  floatx4 bv1 = *(const floatx4*)(bias + col + 4);
  floatx4 h0 = *(const floatx4*)(res + i0);
  floatx4 h1 = *(const floatx4*)(res + i0 + 4);
  floatx4 o0, o1;
  #pragma unroll
  for (int i = 0; i < 4; ++i) {
    float s0 = h0[i] + bv0[i], s1 = h1[i] + bv1[i];
    #pragma unroll
    for (int z = 0; z < NP; ++z) { s0 += b2f(a[z][i]); s1 += b2f(a[z][4+i]); }
    o0[i] = s0; o1[i] = s1;
  }
  *(floatx4*)(out + i0)     = o0;
  *(floatx4*)(out + i0 + 4) = o1;
}

// ---------- launch ----------
extern "C" void kernel_launch(void* const* d_in, const int* in_sizes, int n_in,
                              void* d_out, int out_size, void* d_ws, size_t ws_size,
                              hipStream_t stream) {
  const float* hidden    = (const float*)d_in[0];
  const float* w_attn    = (const float*)d_in[1];
  const float* b_attn    = (const float*)d_in[2];
  const float* w_proj    = (const float*)d_in[3];
  const float* b_proj    = (const float*)d_in[4];
  const float* w_fc      = (const float*)d_in[5];
  const float* b_fc      = (const float*)d_in[6];
  const float* w_fc_proj = (const float*)d_in[7];
  const float* b_fc_proj = (const float*)d_in[8];
  const float* ln1_w     = (const float*)d_in[9];
  const float* ln1_b     = (const float*)d_in[10];
  const float* ln2_w     = (const float*)d_in[11];
  const float* ln2_b     = (const float*)d_in[12];

  // Workspace layout (MB offsets) — round-8/9 verified layout
  char* wsb = (char*)d_ws;
  u16*   qkvb  = (u16*)  (wsb + (size_t)( 0u << 20));  // 24 MB [4096,3072]
  u16*   xb    = (u16*)  (wsb + (size_t)(24u << 20));  //  8 MB [4096,1024]
  u16*   opart = (u16*)  (wsb + (size_t)(24u << 20));  // 16 MB (xb dead)
  float* mlbuf = (float*)(wsb + (size_t)(40u << 20));  //  2 MB
  u16*   attnb = (u16*)  (wsb + (size_t)(42u << 20));  //  8 MB [4096,1024]
  u16*   wqT   = (u16*)  (wsb + (size_t)(50u << 20));  //  6 MB [3072,1024]
  u16*   wpT   = (u16*)  (wsb + (size_t)(56u << 20));  //  2 MB [1024,1024]
  u16*   wfT   = (u16*)  (wsb + (size_t)(58u << 20));  //  8 MB [4096,1024]
  u16*   wfpT  = (u16*)  (wsb + (size_t)(66u << 20));  //  8 MB [1024,4096]
  u16*   pproj = (u16*)  (wsb + (size_t)(24u << 20));  // 16 MB (opart dead)
  float* hbuf  = (float*)(wsb + (size_t)(42u << 20));  // 16 MB fp32
  u16*   yb    = (u16*)  (wsb + (size_t)( 0u << 20));  //  8 MB (qkvb dead)
  u16*   fcb   = (u16*)  (wsb + (size_t)( 8u << 20));  // 32 MB
  u16*   p4    = (u16*)  (wsb + (size_t)(74u << 20));  // BIG: 4x8MB partials
  u16*   pfcp0 = (u16*)  (wsb + (size_t)( 0u << 20));  // fallback z0
  const size_t zstr8  = ((size_t)8u << 20) / 2;        // 8 MB in u16 elems
  const size_t zstr58 = ((size_t)58u << 20) / 2;       // fallback stride

  const bool big = ws_size >= ((size_t)106u << 20);

  // 0) weight transpose+convert
  wtrans4_kernel<<<dim3(12288), 256, 0, stream>>>(
      w_attn, w_proj, w_fc, w_fc_proj, wqT, wpT, wfT, wfpT);

  // 1) x = LN1(hidden) -> bf16
  ln_bf16_kernel<<<4096, 256, 0, stream>>>(hidden, ln1_w, ln1_b, xb);
  // 2) qkv = x @ w_attn + b_attn -> bf16; q pre-scaled (flag 8); 768 blocks
  gemm_mfma_kernel<128,128,12,4, 24,32,1, 2,4,1><<<dim3(24, 32, 1), 256, 0, stream>>>(
      xb, wqT, b_attn, nullptr, qkvb, 4096, 3072, 1024, 1024, 0);
  // 3) flash attention partials (XCD-clustered) + combine
  attn_mfma_kernel<<<dim3(32, 16, 2), 256, 0, stream>>>(qkvb, opart, mlbuf);
  attn_combine_kernel<<<dim3(512, 16, 2), 256, 0, stream>>>(opart, mlbuf, attnb);

  // 4) proj partials: K-split x2, 128x64 tile (round-3 config — best measured)
  gemm_mfma_kernel<128,64,4,4, 16,32,2, 1,4,2><<<dim3(16, 32, 2), 256, 0, stream>>>(
      attnb, wpT, nullptr, nullptr, pproj, 4096, 1024, 1024, 512, zstr8);
  // 4b+5) h = hidden + p0 + p1 + b_proj; y = LN2(h)
  combine_ln_kernel<2><<<4096, 256, 0, stream>>>(
      pproj, zstr8, hidden, b_proj, ln2_w, ln2_b, hbuf, yb);
  // 6) fc = gelu(y @ w_fc + b_fc); 1024 blocks (round-3 config)
  gemm_mfma_kernel<128,128,5,4, 32,32,1, 2,4,1><<<dim3(32, 32, 1), 256, 0, stream>>>(
      yb, wfT, b_fc, nullptr, fcb, 4096, 4096, 1024, 1024, 0);
  if (big) {
    // 7) fc_proj partials: K-split x4, 128x128 tile (round-5 measured −9 µs)
    gemm_mfma_kernel<128,128,4,4, 8,32,4, 1,2,4><<<dim3(8, 32, 4), 256, 0, stream>>>(
        fcb, wfpT, nullptr, nullptr, p4, 4096, 1024, 4096, 1024, zstr8);
    // 8) out = h + sum(p) + b_fc_proj -> fp32
    ksplit_combine_kernel<4><<<dim3(2048), 256, 0, stream>>>(
        p4, zstr8, hbuf, b_fc_proj, (float*)d_out);
  } else {
    gemm_mfma_kernel<128,64,4,4, 16,32,2, 1,4,2><<<dim3(16, 32, 2), 256, 0, stream>>>(
        fcb, wfpT, nullptr, nullptr, pfcp0, 4096, 1024, 4096, 2048, zstr58);
    ksplit_combine_kernel<2><<<dim3(2048), 256, 0, stream>>>(
        pfcp0, zstr58, hbuf, b_fc_proj, (float*)d_out);
  }
}